// Round 7
// baseline (2866.519 us; speedup 1.0000x reference)
//
#include <hip/hip_runtime.h>
#include <hip/hip_bf16.h>

typedef __hip_bfloat16 bf16;
typedef __attribute__((ext_vector_type(8))) short short8;
typedef __attribute__((ext_vector_type(4))) float floatx4;

#define B_    16
#define L_    64
#define N_    1024
#define HANDD 99
#define Jn    21
#define HID   512
#define NLAY  4
#define NHEAD 8
#define DHEAD 64
#define CATD  2273
#define CATP  2304
#define S_    128
#define T_    2048

// float workspace offsets
#define F_X     16
#define F_QKV   1048592
#define F_TMP   6291472
#define F_H     7340048
#define WB_F    8388624
// ushort offsets from wb
#define W_FCL   0
#define W_FCR   1179648
#define W_QKV   2359296
#define W_WO    5505024
#define W_W1    6553600
#define W_W2    10747904
#define U_CATL  14942208
#define U_CATR  17301504
#define U_XB    19660800
#define U_AOB   20709376
#define U_HB    21757952
#define W_OUT   22806528
#define U_FFB   U_CATL   // alias: cat buffers dead after fc

#define RSTR 68
#define VSTR 136
#define NBLK 512           // 2 blocks/CU forced via __launch_bounds__(256,2) -> co-resident
#define SMEMB 52224        // union: attn Vt(17408)+Pb(34816)=52224, gemm 34816, prep 16640

#define PC_UNITS 2048
#define NW_UNITS 3680
#define PREP_UNITS (PC_UNITS + NW_UNITS + 1)

static __device__ __forceinline__ float b2f(bf16 x) { return __bfloat162float(x); }
static __device__ __forceinline__ float ldin(const void* p, size_t i, int isf32) {
    return isf32 ? ((const float*)p)[i] : b2f(((const bf16*)p)[i]);
}
static __device__ __forceinline__ unsigned short f2bf(float f) {
    unsigned int u = __float_as_uint(f);
    unsigned int r = (u + 0x7fffu + ((u >> 16) & 1u)) >> 16;
    return (unsigned short)r;
}

// grid barrier: monotone counter, device scope. Bounded spin: a logic bug
// yields wrong answers, not a hung GPU. Counter zeroed by detect each replay.
// Reader-side __threadfence after the spin = acquire (invalidate stale lines).
static __device__ __forceinline__ void gbar(int* cnt, int target)
{
    __syncthreads();
    if (threadIdx.x == 0) {
        __threadfence();                 // release our writes
        atomicAdd(cnt, 1);
        int spins = 0;
        while (__hip_atomic_load(cnt, __ATOMIC_RELAXED, __HIP_MEMORY_SCOPE_AGENT) < target) {
            __builtin_amdgcn_s_sleep(2);
            if (++spins > (1 << 21)) break;
        }
    }
    __syncthreads();
    __threadfence();                     // acquire side
}

__global__ __launch_bounds__(256) void detect_kernel(const void* mc, int* flag)
{
    __shared__ int sbad;
    int tid = threadIdx.x;
    if (tid == 0) sbad = 0;
    __syncthreads();
    int bad = 0;
    for (int i = tid; i < 16384; i += 256) {
        float v = b2f(((const bf16*)mc)[i]);
        if (!(v >= -0.02f && v <= 1.02f)) bad = 1;
    }
    if (bad) atomicOr(&sbad, 1);
    __syncthreads();
    if (tid == 0) { flag[0] = sbad ? 1 : 0; flag[8] = 0; }   // flag[8] = barrier counter
}

struct MP {
    const void *x_l, *x_r, *j_l, *j_r, *mc, *x_obj, *pc;
    const void *fc_lw, *fc_lb, *fc_rw, *fc_rb;
    const void *out_lw, *out_lb, *out_rw, *out_rb;
    const void *Wqkv, *bqkv, *Wo, *bo, *W1, *b1f, *W2, *b2f2;
    const void *ln1g, *ln1b, *ln2g, *ln2b;
    float* ws; void* out;
};

// ---- prep: pctcat (hand-split) + weight transposes + zero unit ----
static __device__ void pctcat_half(int bl, int hand, const MP& P,
                                   unsigned short* catl, unsigned short* catr,
                                   int isf32, char* smemc)
{
    float* pcl  = (float*)smemc;
    float* pcnl = pcl + N_ * 3;
    int b = bl >> 6;
    int tid = threadIdx.x;

    size_t xo = (size_t)bl * 10;
    float t0 = ldin(P.x_obj, xo+0, isf32), t1 = ldin(P.x_obj, xo+1, isf32), t2 = ldin(P.x_obj, xo+2, isf32);
    float a1x = ldin(P.x_obj, xo+3, isf32), a1y = ldin(P.x_obj, xo+4, isf32), a1z = ldin(P.x_obj, xo+5, isf32);
    float a2x = ldin(P.x_obj, xo+6, isf32), a2y = ldin(P.x_obj, xo+7, isf32), a2z = ldin(P.x_obj, xo+8, isf32);
    float n1 = sqrtf(a1x*a1x + a1y*a1y + a1z*a1z);
    float b1x = a1x / n1, b1y = a1y / n1, b1z = a1z / n1;
    float d = b1x*a2x + b1y*a2y + b1z*a2z;
    float c2x = a2x - d*b1x, c2y = a2y - d*b1y, c2z = a2z - d*b1z;
    float n2 = sqrtf(c2x*c2x + c2y*c2y + c2z*c2z);
    float b2x = c2x / n2, b2y = c2y / n2, b2z = c2z / n2;
    float b3x = b1y*b2z - b1z*b2y;
    float b3y = b1z*b2x - b1x*b2z;
    float b3z = b1x*b2y - b1y*b2x;

    size_t pcb = (size_t)b * N_ * 3;
    for (int n = tid; n < N_; n += 256) {
        float p0 = ldin(P.pc, pcb + n*3+0, isf32);
        float p1 = ldin(P.pc, pcb + n*3+1, isf32);
        float p2 = ldin(P.pc, pcb + n*3+2, isf32);
        float q0 = b1x*p0 + b2x*p1 + b3x*p2 + t0;
        float q1 = b1y*p0 + b2y*p1 + b3y*p2 + t1;
        float q2 = b1z*p0 + b2z*p1 + b3z*p2 + t2;
        pcl[n*3+0] = q0; pcl[n*3+1] = q1; pcl[n*3+2] = q2;
        pcnl[n] = q0*q0 + q1*q1 + q2*q2;
    }
    __syncthreads();

    const void* xh = hand ? P.x_r : P.x_l;
    const void* jh = hand ? P.j_r : P.j_l;
    unsigned short* row = (hand ? catr : catl) + (size_t)bl * CATP;
    for (int c = tid; c < HANDD; c += 256)  row[c]        = f2bf(ldin(xh, (size_t)bl*HANDD + c, isf32));
    for (int c = tid; c < 63;    c += 256)  row[99 + c]   = f2bf(ldin(jh, (size_t)bl*63 + c, isf32));
    for (int c = tid; c < N_;    c += 256)  row[162 + c]  = f2bf(ldin(P.mc, (size_t)b*N_ + c, isf32));
    for (int c = tid; c < N_;    c += 256)  row[1186 + c] = f2bf(sqrtf(pcnl[c]));
    for (int c = CATD + tid; c < CATP; c += 256) row[c] = 0;

    int wave = tid >> 6, lane = tid & 63;
    for (int j = wave; j < Jn; j += 4) {
        float jx = ldin(jh, (size_t)bl*63 + j*3 + 0, isf32);
        float jy = ldin(jh, (size_t)bl*63 + j*3 + 1, isf32);
        float jz = ldin(jh, (size_t)bl*63 + j*3 + 2, isf32);
        float m2x = -2.f * jx, m2y = -2.f * jy, m2z = -2.f * jz;
        float best = 3.4e38f; int bidx = 0x7fffffff;
        for (int n = lane; n < N_; n += 64) {
            float p0 = pcl[n*3+0], p1 = pcl[n*3+1], p2 = pcl[n*3+2];
            float d2 = fmaf(m2x, p0, fmaf(m2y, p1, fmaf(m2z, p2, pcnl[n])));
            if (d2 < best) { best = d2; bidx = n; }
        }
        for (int off = 32; off; off >>= 1) {
            float ob = __shfl_down(best, off, 64);
            int   oi = __shfl_down(bidx, off, 64);
            if (ob < best || (ob == best && oi < bidx)) { best = ob; bidx = oi; }
        }
        bidx = __shfl(bidx, 0, 64);
        if (lane < 3) {
            float jc = (lane == 0) ? jx : ((lane == 1) ? jy : jz);
            float cc = pcl[bidx*3 + lane];
            float dd = jc - cc;
            row[2210 + j*3 + lane] = f2bf(expf(-50.f * dd * dd));
        }
    }
}

// RACE NOTE: transpose write guarded by n < NnB (out_lw/out_rw abut at row 99).
static __device__ void prep_unit(int u, const MP& P, unsigned short* wb,
                                 unsigned short* catl, unsigned short* catr,
                                 int isf32, char* smemc)
{
    if (u < PC_UNITS) { pctcat_half(u >> 1, u & 1, P, catl, catr, isf32, smemc); return; }
    u -= PC_UNITS;
    if (u == NW_UNITS) {
        unsigned short* wz = wb + W_OUT + (size_t)(2 * HANDD) * HID;
        for (int idx = threadIdx.x; idx < (256 - 2 * HANDD) * HID; idx += 256)
            wz[idx] = 0;
        return;
    }
    float (*tile)[65] = (float(*)[65])smemc;
    const void* src; unsigned short* dst;
    int K, Nn, NnB, Kpad, gx; size_t soff = 0, doff = 0;
    if (u < 576) {
        int hh = u >= 288; if (hh) u -= 288;
        src = hh ? P.fc_rw : P.fc_lw; dst = wb + (hh ? W_FCR : W_FCL);
        K = CATD; Nn = HID; NnB = HID; Kpad = CATP; gx = 8;
    } else if (u < 1344) {
        int r = u - 576; int z = r / 192; u = r % 192;
        src = P.Wqkv; soff = (size_t)z * HID * 1536;
        dst = wb + W_QKV; doff = (size_t)z * 1536 * HID;
        K = HID; Nn = 1536; NnB = 1536; Kpad = HID; gx = 24;
    } else if (u < 1600) {
        int r = u - 1344; int z = r / 64; u = r % 64;
        src = P.Wo; soff = (size_t)z * HID * HID;
        dst = wb + W_WO; doff = (size_t)z * HID * HID;
        K = HID; Nn = HID; NnB = HID; Kpad = HID; gx = 8;
    } else if (u < 2624) {
        int r = u - 1600; int z = r / 256; u = r % 256;
        src = P.W1; soff = (size_t)z * HID * 2048;
        dst = wb + W_W1; doff = (size_t)z * 2048 * HID;
        K = HID; Nn = 2048; NnB = 2048; Kpad = HID; gx = 32;
    } else if (u < 3648) {
        int r = u - 2624; int z = r / 256; u = r % 256;
        src = P.W2; soff = (size_t)z * 2048 * HID;
        dst = wb + W_W2; doff = (size_t)z * HID * 2048;
        K = 2048; Nn = HID; NnB = HID; Kpad = 2048; gx = 8;
    } else {
        int r = u - 3648; int hh = r >= 16; if (hh) r -= 16;
        src = hh ? P.out_rw : P.out_lw;
        dst = wb + W_OUT + (hh ? (size_t)HANDD * HID : 0);
        K = HID; Nn = HANDD; NnB = HANDD; Kpad = HID; gx = 2; u = r;
    }
    int n0 = (u % gx) * 64, k0 = (u / gx) * 64;
    int a = threadIdx.x & 63, bq = threadIdx.x >> 6;
    for (int r = bq; r < 64; r += 4) {
        int k = k0 + r, n = n0 + a;
        float v = (k < K && n < NnB) ? ldin(src, soff + (size_t)k * Nn + n, isf32) : 0.f;
        tile[r][a] = v;
    }
    __syncthreads();
    for (int r = bq; r < 64; r += 4) {
        int n = n0 + r;
        if (n < NnB)
            dst[doff + (size_t)n * Kpad + k0 + a] = f2bf(tile[a][r]);
    }
}

// ---- K-split MFMA GEMM phase (unit-strided; port of validated gemm_ks) ----
static __device__ void gemm_phase(
    const unsigned short* __restrict__ Ab0, const unsigned short* __restrict__ Ab2,
    int K,
    const unsigned short* __restrict__ Wt, size_t wtoff0, size_t wtoff2, int halfgrid,
    int Nn,
    const void* bias0, const void* bias20, size_t boff,
    const float* __restrict__ resid,
    float* __restrict__ Df, unsigned short* __restrict__ Db,
    int relu, int rowmap0, int tilesN, int nunits, int isf32, char* smemc)
{
    float* red = (float*)smemc;
    int tid = threadIdx.x;
    int wave = tid >> 6, lane = tid & 63;
    int quad = lane >> 4, l16 = lane & 15;
    int cc = tid & 63;
    int rbase = tid >> 6;

    for (int u = blockIdx.x; u < nunits; u += gridDim.x) {
        int blk = u;
        const unsigned short* Ab = Ab0; size_t wtoff = wtoff0;
        const void* bias = bias0; int rowmap = rowmap0;
        if (halfgrid && blk >= halfgrid) {
            blk -= halfgrid; Ab = Ab2; wtoff = wtoff2; bias = bias20; rowmap = 2;
        }
        int tm = blk / tilesN, tn = blk - tm * tilesN;
        int row0 = tm << 6, col0 = tn << 6;
        int Ks = K >> 2;
        int ks0 = wave * Ks;

        const unsigned short* Ap = Ab + (size_t)(row0 + l16) * K + ks0 + quad * 8;
        const unsigned short* Bp = Wt + wtoff + (size_t)(col0 + l16) * K + ks0 + quad * 8;
        size_t astep = (size_t)16 * K;

        floatx4 acc[4][4];
        #pragma unroll
        for (int i = 0; i < 4; i++)
            #pragma unroll
            for (int j = 0; j < 4; j++)
                acc[i][j] = (floatx4){0.f, 0.f, 0.f, 0.f};

        for (int k = 0; k < Ks; k += 32) {
            short8 af[4], bf[4];
            #pragma unroll
            for (int i = 0; i < 4; i++) {
                af[i] = *(const short8*)(Ap + i * astep + k);
                bf[i] = *(const short8*)(Bp + i * astep + k);
            }
            #pragma unroll
            for (int mi = 0; mi < 4; mi++)
                #pragma unroll
                for (int ni = 0; ni < 4; ni++)
                    acc[mi][ni] = __builtin_amdgcn_mfma_f32_16x16x32_bf16(
                        af[mi], bf[ni], acc[mi][ni], 0, 0, 0);
        }

        int c = col0 + cc;
        float bv;
        if (rowmap == 3)
            bv = (c < HANDD) ? ldin(bias, c, isf32)
               : ((c < 2 * HANDD) ? ldin(bias20, c - HANDD, isf32) : 0.f);
        else
            bv = bias ? ldin(bias, boff + c, isf32) : 0.f;
        float pe_div = 0.f, pa = 0.f;
        if (rowmap == 1 || rowmap == 2) {
            int ci = c & ~1;
            pe_div = expf((float)ci * (-logf(10000.f) / (float)HID));
            int hand = rowmap - 1;
            pa = (c & 1) ? cosf((float)hand * pe_div) : sinf((float)hand * pe_div);
        }

        #pragma unroll
        for (int s = 0; s < 2; s++) {
            #pragma unroll
            for (int mi2 = 0; mi2 < 2; mi2++) {
                int mi = s * 2 + mi2;
                #pragma unroll
                for (int ni = 0; ni < 4; ni++)
                    #pragma unroll
                    for (int reg = 0; reg < 4; reg++) {
                        int r = mi2 * 16 + quad * 4 + reg;
                        int col = ni * 16 + l16;
                        red[wave * (32 * RSTR) + r * RSTR + col] = acc[mi][ni][reg];
                    }
            }
            __syncthreads();

            #pragma unroll
            for (int j = 0; j < 8; j++) {
                int rr = rbase + (j << 2);
                int idx = rr * RSTR + cc;
                float v = red[0*(32*RSTR)+idx] + red[1*(32*RSTR)+idx]
                        + red[2*(32*RSTR)+idx] + red[3*(32*RSTR)+idx] + bv;
                int r = row0 + s * 32 + rr;
                if (resid) v += resid[(size_t)r * Nn + c];
                if (relu)  v = fmaxf(v, 0.f);
                if (rowmap == 3) {
                    int hand = r & 1;
                    int l = (r >> 1) & 63, bb2 = r >> 7;
                    if (hand == 0 && c < HANDD) {
                        size_t oi = ((size_t)bb2 * 64 + l) * HANDD + c;
                        if (isf32) ((float*)Df)[oi] = v;
                        else       ((bf16*)Df)[oi]  = __float2bfloat16(v);
                    } else if (hand == 1 && c >= HANDD && c < 2 * HANDD) {
                        size_t oi = (size_t)B_ * L_ * HANDD + ((size_t)bb2 * 64 + l) * HANDD + (c - HANDD);
                        if (isf32) ((float*)Df)[oi] = v;
                        else       ((bf16*)Df)[oi]  = __float2bfloat16(v);
                    }
                } else {
                    int orow = r;
                    if (rowmap) {
                        int bb2 = r >> 6, ll = r & 63;
                        orow = bb2 * S_ + 2 * ll + (rowmap - 1);
                        float pf = (c & 1) ? cosf((float)ll * pe_div) : sinf((float)ll * pe_div);
                        v += pf + pa;
                    }
                    if (Df) Df[(size_t)orow * Nn + c] = v;
                    if (Db) Db[(size_t)orow * Nn + c] = f2bf(v);
                }
            }
            __syncthreads();   // red reuse (stage 1 / next unit)
        }
    }
}

// ---- attention phase: proven attn_mfma body, 256 threads = (rowhalf, w2) ----
static __device__ void attn_phase(const unsigned short* __restrict__ qkvb,
                                  unsigned short* __restrict__ aob, char* smemc)
{
    unsigned short* Vt = (unsigned short*)smemc;   // [64 dcol][VSTR]
    unsigned short* Pb = Vt + 64 * VSTR;           // [128 qrow][VSTR]
    int tid = threadIdx.x;
    int w = tid >> 6, lane = tid & 63;
    int rh = w >> 1, w2 = w & 1;                   // rowhalf, wave-within-half
    int quad = lane >> 4, l16 = lane & 15;

    for (int bh = blockIdx.x; bh < B_ * NHEAD; bh += gridDim.x) {
        int b = bh >> 3, hh = bh & 7;
        size_t qbase = (size_t)(b * S_) * 1536 + hh * DHEAD;

        for (int i = tid; i < S_ * DHEAD; i += 256) {
            int key = i >> 6, dcol = i & 63;
            Vt[dcol * VSTR + key] = qkvb[qbase + (size_t)key * 1536 + 1024 + dcol];
        }
        __syncthreads();

        int qrow0 = rh * 64 + w2 * 32;
        short8 aQ[2][2];
        #pragma unroll
        for (int mt = 0; mt < 2; mt++)
            #pragma unroll
            for (int kc = 0; kc < 2; kc++)
                aQ[mt][kc] = *(const short8*)&qkvb[qbase + (size_t)(qrow0 + mt*16 + l16) * 1536 + kc*32 + quad*8];

        floatx4 sacc[2][8];
        #pragma unroll
        for (int mt = 0; mt < 2; mt++)
            #pragma unroll
            for (int nt = 0; nt < 8; nt++)
                sacc[mt][nt] = (floatx4){0.f, 0.f, 0.f, 0.f};

        #pragma unroll
        for (int nt = 0; nt < 8; nt++) {
            const unsigned short* kp = &qkvb[qbase + (size_t)(nt*16 + l16) * 1536 + 512 + quad*8];
            short8 bK0 = *(const short8*)kp;
            short8 bK1 = *(const short8*)(kp + 32);
            #pragma unroll
            for (int mt = 0; mt < 2; mt++) {
                sacc[mt][nt] = __builtin_amdgcn_mfma_f32_16x16x32_bf16(aQ[mt][0], bK0, sacc[mt][nt], 0, 0, 0);
                sacc[mt][nt] = __builtin_amdgcn_mfma_f32_16x16x32_bf16(aQ[mt][1], bK1, sacc[mt][nt], 0, 0, 0);
            }
        }

        #pragma unroll
        for (int mt = 0; mt < 2; mt++)
            #pragma unroll
            for (int reg = 0; reg < 4; reg++) {
                float v[8];
                float m = -3.4e38f;
                #pragma unroll
                for (int nt = 0; nt < 8; nt++) { v[nt] = sacc[mt][nt][reg] * 0.125f; m = fmaxf(m, v[nt]); }
                #pragma unroll
                for (int off = 1; off <= 8; off <<= 1) m = fmaxf(m, __shfl_xor(m, off, 64));
                float sum = 0.f;
                #pragma unroll
                for (int nt = 0; nt < 8; nt++) { v[nt] = expf(v[nt] - m); sum += v[nt]; }
                #pragma unroll
                for (int off = 1; off <= 8; off <<= 1) sum += __shfl_xor(sum, off, 64);
                float inv = 1.f / sum;
                int lr = qrow0 + mt*16 + quad*4 + reg;     // 0..127
                #pragma unroll
                for (int nt = 0; nt < 8; nt++)
                    Pb[lr * VSTR + nt*16 + l16] = f2bf(v[nt] * inv);
            }
        __syncthreads();

        #pragma unroll
        for (int mt = 0; mt < 2; mt++) {
            short8 aP[4];
            #pragma unroll
            for (int kt = 0; kt < 4; kt++)
                aP[kt] = *(const short8*)&Pb[(qrow0 + mt*16 + l16) * VSTR + kt*32 + quad*8];
            #pragma unroll
            for (int nt = 0; nt < 4; nt++) {
                floatx4 o = (floatx4){0.f, 0.f, 0.f, 0.f};
                #pragma unroll
                for (int kt = 0; kt < 4; kt++) {
                    short8 bV = *(const short8*)&Vt[(nt*16 + l16) * VSTR + kt*32 + quad*8];
                    o = __builtin_amdgcn_mfma_f32_16x16x32_bf16(aP[kt], bV, o, 0, 0, 0);
                }
                #pragma unroll
                for (int reg = 0; reg < 4; reg++) {
                    int qrow = qrow0 + mt*16 + quad*4 + reg;
                    aob[(size_t)(b*S_ + qrow) * HID + hh*DHEAD + nt*16 + l16] = f2bf(o[reg]);
                }
            }
        }
        __syncthreads();   // Vt/Pb reuse next unit
    }
}

// ---- LayerNorm phase: proven block-per-row body, unit-strided ----
static __device__ void ln_phase(const float* __restrict__ src, const void* __restrict__ g,
                                const void* __restrict__ bb, size_t goff,
                                float* __restrict__ dst, unsigned short* __restrict__ dstb,
                                int isf32, char* smemc)
{
    float* wsum = (float*)smemc;
    int tid = threadIdx.x, lane = tid & 63, wave = tid >> 6;
    for (int t = blockIdx.x; t < T_; t += gridDim.x) {
        const float* x = src + (size_t)t * HID;
        float v0 = x[tid], v1 = x[tid + 256];
        float s = v0 + v1;
        for (int off = 32; off; off >>= 1) s += __shfl_down(s, off, 64);
        if (lane == 0) wsum[wave] = s;
        __syncthreads();
        float mu = (wsum[0] + wsum[1] + wsum[2] + wsum[3]) * (1.f / 512.f);
        float d0 = v0 - mu, d1 = v1 - mu;
        float q = d0 * d0 + d1 * d1;
        for (int off = 32; off; off >>= 1) q += __shfl_down(q, off, 64);
        __syncthreads();
        if (lane == 0) wsum[wave] = q;
        __syncthreads();
        float var = (wsum[0] + wsum[1] + wsum[2] + wsum[3]) * (1.f / 512.f);
        float rstd = 1.f / sqrtf(var + 1e-5f);
        float y0 = d0 * rstd * ldin(g, goff + tid, isf32)       + ldin(bb, goff + tid, isf32);
        float y1 = d1 * rstd * ldin(g, goff + tid + 256, isf32) + ldin(bb, goff + tid + 256, isf32);
        dst[(size_t)t * HID + tid]        = y0;
        dst[(size_t)t * HID + tid + 256]  = y1;
        dstb[(size_t)t * HID + tid]       = f2bf(y0);
        dstb[(size_t)t * HID + tid + 256] = f2bf(y1);
        __syncthreads();   // wsum reuse next unit
    }
}

// ---- the persistent kernel: 2 blocks/CU forced -> all 512 co-resident ----
__global__ __launch_bounds__(256, 2) void mega_kernel(MP P)
{
    __shared__ __attribute__((aligned(16))) char smem[SMEMB];
    float* ws  = P.ws;
    int* dtf = (int*)ws;
    int* bar = dtf + 8;
    int NB = (int)gridDim.x;
    int ph = 0;
    int isf32 = dtf[0];

    float* x   = ws + F_X;
    float* tmp = ws + F_TMP;
    float* h   = ws + F_H;
    unsigned short* qkvb = (unsigned short*)(ws + F_QKV);
    unsigned short* wb   = (unsigned short*)(ws + WB_F);
    unsigned short* catl = wb + U_CATL;
    unsigned short* catr = wb + U_CATR;
    unsigned short* xb   = wb + U_XB;
    unsigned short* aob  = wb + U_AOB;
    unsigned short* hb   = wb + U_HB;
    unsigned short* ffb  = wb + U_FFB;

    for (int u = blockIdx.x; u < PREP_UNITS; u += NB) {
        prep_unit(u, P, wb, catl, catr, isf32, smem);
        __syncthreads();
    }
    gbar(bar, ++ph * NB);

    gemm_phase(catl, catr, CATP, wb, W_FCL, W_FCR, 128, HID,
               P.fc_lb, P.fc_rb, 0, nullptr, x, xb, 0, 1, 8, 256, isf32, smem);
    gbar(bar, ++ph * NB);

    for (int i = 0; i < NLAY; i++) {
        size_t oWq = (size_t)W_QKV + (size_t)i * 1536 * HID, obq = (size_t)i * 1536;
        size_t oWo = (size_t)W_WO + (size_t)i * HID * HID,   obo = (size_t)i * HID;
        size_t oW1 = (size_t)W_W1 + (size_t)i * 2048 * HID,  ob1 = (size_t)i * 2048;
        size_t oW2 = (size_t)W_W2 + (size_t)i * HID * 2048,  ob2 = (size_t)i * HID;
        size_t oln = (size_t)i * HID;

        gemm_phase(xb, nullptr, HID, wb, oWq, 0, 0, 1536,
                   P.bqkv, nullptr, obq, nullptr, nullptr, qkvb, 0, 0, 24, 768, isf32, smem);
        gbar(bar, ++ph * NB);

        attn_phase(qkvb, aob, smem);
        gbar(bar, ++ph * NB);

        gemm_phase(aob, nullptr, HID, wb, oWo, 0, 0, HID,
                   P.bo, nullptr, obo, x, tmp, nullptr, 0, 0, 8, 256, isf32, smem);
        gbar(bar, ++ph * NB);

        ln_phase(tmp, P.ln1g, P.ln1b, oln, h, hb, isf32, smem);
        gbar(bar, ++ph * NB);

        gemm_phase(hb, nullptr, HID, wb, oW1, 0, 0, 2048,
                   P.b1f, nullptr, ob1, nullptr, nullptr, ffb, 1, 0, 32, 1024, isf32, smem);
        gbar(bar, ++ph * NB);

        gemm_phase(ffb, nullptr, 2048, wb, oW2, 0, 0, HID,
                   P.b2f2, nullptr, ob2, h, tmp, nullptr, 0, 0, 8, 256, isf32, smem);
        gbar(bar, ++ph * NB);

        ln_phase(tmp, P.ln2g, P.ln2b, oln, x, xb, isf32, smem);
        gbar(bar, ++ph * NB);
    }

    gemm_phase(xb, nullptr, HID, wb, W_OUT, 0, 0, 256,
               P.out_lb, P.out_rb, 0, nullptr, (float*)P.out, nullptr, 0, 3, 4, 128, isf32, smem);
}

extern "C" void kernel_launch(void* const* d_in, const int* in_sizes, int n_in,
                              void* d_out, int out_size, void* d_ws, size_t ws_size,
                              hipStream_t stream)
{
    MP P;
    P.x_l = d_in[0];  P.x_r = d_in[1];
    P.j_l = d_in[2];  P.j_r = d_in[3];
    P.mc  = d_in[4];  P.x_obj = d_in[5]; P.pc = d_in[6];
    P.fc_lw = d_in[7];  P.fc_lb = d_in[8];
    P.fc_rw = d_in[9];  P.fc_rb = d_in[10];
    P.out_lw = d_in[11]; P.out_lb = d_in[12];
    P.out_rw = d_in[13]; P.out_rb = d_in[14];
    P.Wqkv = d_in[15]; P.bqkv = d_in[16];
    P.Wo = d_in[17];   P.bo = d_in[18];
    P.W1 = d_in[19];   P.b1f = d_in[20];
    P.W2 = d_in[21];   P.b2f2 = d_in[22];
    P.ln1g = d_in[23]; P.ln1b = d_in[24];
    P.ln2g = d_in[25]; P.ln2b = d_in[26];
    P.ws = (float*)d_ws; P.out = d_out;

    detect_kernel<<<1, 256, 0, stream>>>(P.mc, (int*)d_ws);
    mega_kernel<<<NBLK, 256, 0, stream>>>(P);
}

// Round 9
// 1071.381 us; speedup vs baseline: 2.6755x; 2.6755x over previous
//
#include <hip/hip_runtime.h>
#include <hip/hip_bf16.h>

typedef __hip_bfloat16 bf16;
typedef __attribute__((ext_vector_type(8))) short short8;
typedef __attribute__((ext_vector_type(4))) float floatx4;

#define B_    16
#define L_    64
#define N_    1024
#define HANDD 99
#define Jn    21
#define HID   512
#define NLAY  4
#define NHEAD 8
#define DHEAD 64
#define CATD  2273
#define CATP  2304
#define S_    128
#define T_    2048

// float workspace offsets
#define F_X     16
#define F_QKV   1048592     // qkvb: 2048x1536 bf16 = 1,572,864 floats -> ends 2,621,456
#define F_CNT   4000000     // 256 ints: ln-fusion tile counters. MUST sit in the
                            // free hole [2,621,456, 6,291,472) — 2,000,000 was
                            // INSIDE qkvb and got overwritten every layer (r8 bug).
#define F_TMP   6291472
#define F_H     7340048
#define WB_F    8388624
// ushort offsets from wb
#define W_FCL   0
#define W_FCR   1179648
#define W_QKV   2359296
#define W_WO    5505024
#define W_W1    6553600
#define W_W2    10747904
#define U_CATL  14942208
#define U_CATR  17301504
#define U_XB    19660800
#define U_AOB   20709376
#define U_HB    21757952
#define W_OUT   22806528
#define U_FFB   U_CATL   // alias: cat buffers dead after fc

#define RSTR 68
#define VSTR 136

// prep_all unit space
#define PC_UNITS 2048      // (b,l) x hand
#define NW_UNITS 3680      // transpose tiles
#define PREP_UNITS (PC_UNITS + NW_UNITS + 1)

static __device__ __forceinline__ float b2f(bf16 x) { return __bfloat162float(x); }
static __device__ __forceinline__ float ldin(const void* p, size_t i, int isf32) {
    return isf32 ? ((const float*)p)[i] : b2f(((const bf16*)p)[i]);
}
static __device__ __forceinline__ unsigned short f2bf(float f) {
    unsigned int u = __float_as_uint(f);
    unsigned int r = (u + 0x7fffu + ((u >> 16) & 1u)) >> 16;
    return (unsigned short)r;
}

// ---- merged prep: dtype-detect + pctcat (hand-split) + weight transposes ----
struct PrepP {
    const void *x_l, *x_r, *j_l, *j_r, *mc, *x_obj, *pc;
    const void *fc_lw, *fc_rw, *Wqkv, *Wo, *W1, *W2, *out_lw, *out_rw;
    unsigned short *wb, *catl, *catr;
    int* dtf; int* lncnt;
};

// one (b,l,hand): pc transform + feature row + NN-contact for 21 joints
static __device__ void pctcat_half(int bl, int hand, const PrepP& P, int isf32,
                                   char* smemc)
{
    float* pcl  = (float*)smemc;    // N_*3
    float* pcnl = pcl + N_ * 3;     // N_ (|p|^2)
    int b = bl >> 6;
    int tid = threadIdx.x;

    size_t xo = (size_t)bl * 10;
    float t0 = ldin(P.x_obj, xo+0, isf32), t1 = ldin(P.x_obj, xo+1, isf32), t2 = ldin(P.x_obj, xo+2, isf32);
    float a1x = ldin(P.x_obj, xo+3, isf32), a1y = ldin(P.x_obj, xo+4, isf32), a1z = ldin(P.x_obj, xo+5, isf32);
    float a2x = ldin(P.x_obj, xo+6, isf32), a2y = ldin(P.x_obj, xo+7, isf32), a2z = ldin(P.x_obj, xo+8, isf32);
    float n1 = sqrtf(a1x*a1x + a1y*a1y + a1z*a1z);
    float b1x = a1x / n1, b1y = a1y / n1, b1z = a1z / n1;
    float d = b1x*a2x + b1y*a2y + b1z*a2z;
    float c2x = a2x - d*b1x, c2y = a2y - d*b1y, c2z = a2z - d*b1z;
    float n2 = sqrtf(c2x*c2x + c2y*c2y + c2z*c2z);
    float b2x = c2x / n2, b2y = c2y / n2, b2z = c2z / n2;
    float b3x = b1y*b2z - b1z*b2y;
    float b3y = b1z*b2x - b1x*b2z;
    float b3z = b1x*b2y - b1y*b2x;

    size_t pcb = (size_t)b * N_ * 3;
    for (int n = tid; n < N_; n += 256) {
        float p0 = ldin(P.pc, pcb + n*3+0, isf32);
        float p1 = ldin(P.pc, pcb + n*3+1, isf32);
        float p2 = ldin(P.pc, pcb + n*3+2, isf32);
        float q0 = b1x*p0 + b2x*p1 + b3x*p2 + t0;
        float q1 = b1y*p0 + b2y*p1 + b3y*p2 + t1;
        float q2 = b1z*p0 + b2z*p1 + b3z*p2 + t2;
        pcl[n*3+0] = q0; pcl[n*3+1] = q1; pcl[n*3+2] = q2;
        pcnl[n] = q0*q0 + q1*q1 + q2*q2;
    }
    __syncthreads();

    const void* xh = hand ? P.x_r : P.x_l;
    const void* jh = hand ? P.j_r : P.j_l;
    unsigned short* row = (hand ? P.catr : P.catl) + (size_t)bl * CATP;
    if (!isf32) {
        // bf16 inputs: raw ushort copies, no conversion (f2bf(b2f(x)) == x)
        const unsigned short* xs = (const unsigned short*)xh + (size_t)bl * HANDD;
        const unsigned short* js = (const unsigned short*)jh + (size_t)bl * 63;
        const unsigned short* ms = (const unsigned short*)P.mc + (size_t)b * N_;
        for (int c = tid; c < HANDD; c += 256)  row[c]       = xs[c];
        for (int c = tid; c < 63;    c += 256)  row[99 + c]  = js[c];
        for (int c = tid; c < N_;    c += 256)  row[162 + c] = ms[c];
    } else {
        for (int c = tid; c < HANDD; c += 256)  row[c]       = f2bf(ldin(xh, (size_t)bl*HANDD + c, isf32));
        for (int c = tid; c < 63;    c += 256)  row[99 + c]  = f2bf(ldin(jh, (size_t)bl*63 + c, isf32));
        for (int c = tid; c < N_;    c += 256)  row[162 + c] = f2bf(ldin(P.mc, (size_t)b*N_ + c, isf32));
    }
    for (int c = tid; c < N_;    c += 256)  row[1186 + c] = f2bf(sqrtf(pcnl[c]));
    for (int c = CATD + tid; c < CATP; c += 256) row[c] = 0;

    int wave = tid >> 6, lane = tid & 63;
    for (int j = wave; j < Jn; j += 4) {
        float jx = ldin(jh, (size_t)bl*63 + j*3 + 0, isf32);
        float jy = ldin(jh, (size_t)bl*63 + j*3 + 1, isf32);
        float jz = ldin(jh, (size_t)bl*63 + j*3 + 2, isf32);
        float m2x = -2.f * jx, m2y = -2.f * jy, m2z = -2.f * jz;
        float best = 3.4e38f; int bidx = 0x7fffffff;
        for (int n = lane; n < N_; n += 64) {
            float p0 = pcl[n*3+0], p1 = pcl[n*3+1], p2 = pcl[n*3+2];
            float d2 = fmaf(m2x, p0, fmaf(m2y, p1, fmaf(m2z, p2, pcnl[n])));
            if (d2 < best) { best = d2; bidx = n; }
        }
        for (int off = 32; off; off >>= 1) {
            float ob = __shfl_down(best, off, 64);
            int   oi = __shfl_down(bidx, off, 64);
            if (ob < best || (ob == best && oi < bidx)) { best = ob; bidx = oi; }
        }
        bidx = __shfl(bidx, 0, 64);
        if (lane < 3) {
            float jc = (lane == 0) ? jx : ((lane == 1) ? jy : jz);
            float cc = pcl[bidx*3 + lane];
            float dd = jc - cc;
            row[2210 + j*3 + lane] = f2bf(expf(-50.f * dd * dd));
        }
    }
}

// RACE NOTE (transpose): write guarded by n < NnB. out_lw/out_rw regions abut
// at row 99 (not 64-aligned); unguarded pad writes from the out_lw tiles would
// race with out_rw's real rows 99..127 inside this single dispatch.
__global__ __launch_bounds__(256) void prep_all(PrepP P)
{
    __shared__ __attribute__((aligned(16))) char smem[16640];
    __shared__ int sbad;
    int tid = threadIdx.x;

    // dtype detect (per block; 32KB L2-resident scan)
    if (tid == 0) sbad = 0;
    __syncthreads();
    {
        int bad = 0;
        for (int i = tid; i < 16384; i += 256) {
            float v = b2f(((const bf16*)P.mc)[i]);
            if (!(v >= -0.02f && v <= 1.02f)) bad = 1;
        }
        if (bad) atomicOr(&sbad, 1);
    }
    __syncthreads();
    int isf32 = sbad;
    if (tid == 0 && blockIdx.x == 0) P.dtf[0] = isf32;
    __syncthreads();

    int u = blockIdx.x;
    if (u < PC_UNITS) {                 // pctcat: (b,l) x hand
        pctcat_half(u >> 1, u & 1, P, isf32, smem);
        return;
    }
    u -= PC_UNITS;
    if (u == NW_UNITS) {                // zero Wcomb garbage rows + ln counters
        unsigned short* wz = P.wb + W_OUT + (size_t)(2 * HANDD) * HID;
        for (int idx = tid; idx < (256 - 2 * HANDD) * HID; idx += 256)
            wz[idx] = 0;
        if (tid < 256) P.lncnt[tid] = 0;
        return;
    }

    const void* src; unsigned short* dst;
    int K, Nn, NnB, Kpad, gx; size_t soff = 0, doff = 0;
    if (u < 576) {
        int hh = u >= 288; if (hh) u -= 288;
        src = hh ? P.fc_rw : P.fc_lw; dst = P.wb + (hh ? W_FCR : W_FCL);
        K = CATD; Nn = HID; NnB = HID; Kpad = CATP; gx = 8;
    } else if (u < 1344) {
        int r = u - 576; int z = r / 192; u = r % 192;
        src = P.Wqkv; soff = (size_t)z * HID * 1536;
        dst = P.wb + W_QKV; doff = (size_t)z * 1536 * HID;
        K = HID; Nn = 1536; NnB = 1536; Kpad = HID; gx = 24;
    } else if (u < 1600) {
        int r = u - 1344; int z = r / 64; u = r % 64;
        src = P.Wo; soff = (size_t)z * HID * HID;
        dst = P.wb + W_WO; doff = (size_t)z * HID * HID;
        K = HID; Nn = HID; NnB = HID; Kpad = HID; gx = 8;
    } else if (u < 2624) {
        int r = u - 1600; int z = r / 256; u = r % 256;
        src = P.W1; soff = (size_t)z * HID * 2048;
        dst = P.wb + W_W1; doff = (size_t)z * 2048 * HID;
        K = HID; Nn = 2048; NnB = 2048; Kpad = HID; gx = 32;
    } else if (u < 3648) {
        int r = u - 2624; int z = r / 256; u = r % 256;
        src = P.W2; soff = (size_t)z * 2048 * HID;
        dst = P.wb + W_W2; doff = (size_t)z * HID * 2048;
        K = 2048; Nn = HID; NnB = HID; Kpad = 2048; gx = 8;
    } else {
        int r = u - 3648; int hh = r >= 16; if (hh) r -= 16;
        src = hh ? P.out_rw : P.out_lw;
        dst = P.wb + W_OUT + (hh ? (size_t)HANDD * HID : 0);
        K = HID; Nn = HANDD; NnB = HANDD; Kpad = HID; gx = 2; u = r;
    }
    int n0 = (u % gx) * 64, k0 = (u / gx) * 64;

    if (!isf32 && (Nn % 8) == 0) {
        // bf16 fast path: raw ushort transpose, short8 global IO, no cvt.
        // tu stride 68 ushorts (136B): column reads land 2 lanes/bank (free).
        unsigned short (*tu)[68] = (unsigned short(*)[68])smem;
        const unsigned short* s = (const unsigned short*)src;
        #pragma unroll
        for (int pass = 0; pass < 2; pass++) {
            int r = (tid >> 3) + pass * 32;
            int k = k0 + r;
            int nb = (tid & 7) * 8;
            short8 v = (short8){0,0,0,0,0,0,0,0};
            if (k < K) v = *(const short8*)(s + soff + (size_t)k * Nn + n0 + nb);
            #pragma unroll
            for (int j = 0; j < 8; j++) tu[r][nb + j] = (unsigned short)v[j];
        }
        __syncthreads();
        #pragma unroll
        for (int pass = 0; pass < 2; pass++) {
            int rp = (tid >> 3) + pass * 32;
            int n = n0 + rp;
            int kb = (tid & 7) * 8;
            if (n < NnB) {
                short8 o;
                #pragma unroll
                for (int j = 0; j < 8; j++) o[j] = (short)tu[kb + j][rp];
                *(short8*)(dst + doff + (size_t)n * Kpad + k0 + kb) = o;
            }
        }
    } else {
        // f32 (or narrow) path: scalar via f32 LDS tile (round-5 proven)
        float (*tile)[65] = (float(*)[65])smem;
        int a = tid & 63, bq = tid >> 6;
        for (int r = bq; r < 64; r += 4) {
            int k = k0 + r, n = n0 + a;
            float v = (k < K && n < NnB) ? ldin(src, soff + (size_t)k * Nn + n, isf32) : 0.f;
            tile[r][a] = v;
        }
        __syncthreads();
        for (int r = bq; r < 64; r += 4) {
            int n = n0 + r;
            if (n < NnB)
                dst[doff + (size_t)n * Kpad + k0 + a] = f2bf(tile[a][r]);
        }
    }
}

// K-split MFMA GEMM: one 64x64 tile per block, 4 waves each take K/4,
// two-stage LDS reduce (34.8KB). rowmap: 0 plain, 1/2 fc scatter+PE, 3
// out-proj parity. halfgrid: fc two-hand. Optional fused-LN cleanup: when
// lncnt != nullptr, each block bumps its row-tile counter (release fence +
// device atomic — no spinning); the LAST of tilesN blocks per row-tile
// LayerNorms the 64 rows of Df -> lndst/lndstb. Counters pre-zeroed by prep.
__global__ __launch_bounds__(256) void gemm_ks(
    const unsigned short* __restrict__ Ab, const unsigned short* __restrict__ Ab2,
    int K,
    const unsigned short* __restrict__ Wt, size_t wtoff, size_t wtoff2, int halfgrid,
    int Nn,
    const void* __restrict__ bias, const void* __restrict__ bias2, size_t boff,
    const float* __restrict__ resid,
    float* __restrict__ Df, unsigned short* __restrict__ Db,
    int relu, int rowmap, int tilesN,
    const void* __restrict__ lng, const void* __restrict__ lnb, size_t lnoff,
    float* __restrict__ lndst, unsigned short* __restrict__ lndstb, int* __restrict__ lncnt,
    const int* __restrict__ dtf)
{
    __shared__ float red[4][32 * RSTR];
    int blk = blockIdx.x;
    if (halfgrid && blk >= halfgrid) {
        blk -= halfgrid; Ab = Ab2; wtoff = wtoff2; bias = bias2; rowmap = 2;
    }
    int tid = threadIdx.x;
    int wave = tid >> 6, lane = tid & 63;
    int quad = lane >> 4, l16 = lane & 15;
    int tm = blk / tilesN, tn = blk - tm * tilesN;
    int row0 = tm << 6, col0 = tn << 6;
    int Ks = K >> 2;
    int ks0 = wave * Ks;

    const unsigned short* Ap = Ab + (size_t)(row0 + l16) * K + ks0 + quad * 8;
    const unsigned short* Bp = Wt + wtoff + (size_t)(col0 + l16) * K + ks0 + quad * 8;
    size_t astep = (size_t)16 * K;

    floatx4 acc[4][4];
    #pragma unroll
    for (int i = 0; i < 4; i++)
        #pragma unroll
        for (int j = 0; j < 4; j++)
            acc[i][j] = (floatx4){0.f, 0.f, 0.f, 0.f};

    for (int k = 0; k < Ks; k += 32) {
        short8 af[4], bf[4];
        #pragma unroll
        for (int i = 0; i < 4; i++) {
            af[i] = *(const short8*)(Ap + i * astep + k);
            bf[i] = *(const short8*)(Bp + i * astep + k);
        }
        #pragma unroll
        for (int mi = 0; mi < 4; mi++)
            #pragma unroll
            for (int ni = 0; ni < 4; ni++)
                acc[mi][ni] = __builtin_amdgcn_mfma_f32_16x16x32_bf16(
                    af[mi], bf[ni], acc[mi][ni], 0, 0, 0);
    }

    // per-column epilogue constants
    int isf32 = dtf[0];
    int cc = tid & 63;
    int c = col0 + cc;
    float bv;
    if (rowmap == 3)
        bv = (c < HANDD) ? ldin(bias, c, isf32)
           : ((c < 2 * HANDD) ? ldin(bias2, c - HANDD, isf32) : 0.f);
    else
        bv = bias ? ldin(bias, boff + c, isf32) : 0.f;
    float pe_div = 0.f, pa = 0.f;
    if (rowmap == 1 || rowmap == 2) {
        int ci = c & ~1;
        pe_div = expf((float)ci * (-logf(10000.f) / (float)HID));
        int hand = rowmap - 1;
        pa = (c & 1) ? cosf((float)hand * pe_div) : sinf((float)hand * pe_div);
    }
    int rbase = tid >> 6;

    #pragma unroll
    for (int s = 0; s < 2; s++) {
        #pragma unroll
        for (int mi2 = 0; mi2 < 2; mi2++) {
            int mi = s * 2 + mi2;
            #pragma unroll
            for (int ni = 0; ni < 4; ni++)
                #pragma unroll
                for (int reg = 0; reg < 4; reg++) {
                    int r = mi2 * 16 + quad * 4 + reg;   // 0..31
                    int col = ni * 16 + l16;
                    red[wave][r * RSTR + col] = acc[mi][ni][reg];
                }
        }
        __syncthreads();

        #pragma unroll
        for (int j = 0; j < 8; j++) {
            int rr = rbase + (j << 2);   // 0..31
            int idx = rr * RSTR + cc;
            float v = red[0][idx] + red[1][idx] + red[2][idx] + red[3][idx] + bv;
            int r = row0 + s * 32 + rr;
            if (resid) v += resid[(size_t)r * Nn + c];
            if (relu)  v = fmaxf(v, 0.f);
            if (rowmap == 3) {
                int hand = r & 1;
                int l = (r >> 1) & 63, bb = r >> 7;
                if (hand == 0 && c < HANDD) {
                    size_t oi = ((size_t)bb * 64 + l) * HANDD + c;
                    if (isf32) ((float*)Df)[oi] = v;
                    else       ((bf16*)Df)[oi]  = __float2bfloat16(v);
                } else if (hand == 1 && c >= HANDD && c < 2 * HANDD) {
                    size_t oi = (size_t)B_ * L_ * HANDD + ((size_t)bb * 64 + l) * HANDD + (c - HANDD);
                    if (isf32) ((float*)Df)[oi] = v;
                    else       ((bf16*)Df)[oi]  = __float2bfloat16(v);
                }
            } else {
                int orow = r;
                if (rowmap) {
                    int bb = r >> 6, ll = r & 63;
                    orow = bb * S_ + 2 * ll + (rowmap - 1);
                    float pf = (c & 1) ? cosf((float)ll * pe_div) : sinf((float)ll * pe_div);
                    v += pf + pa;
                }
                if (Df) Df[(size_t)orow * Nn + c] = v;
                if (Db) Db[(size_t)orow * Nn + c] = f2bf(v);
            }
        }
        if (s == 0) __syncthreads();   // red reused by stage 1
    }

    // ---- fused LN cleanup (last arriving block per row-tile) ----
    if (lncnt) {
        __syncthreads();               // all stores of this block drained
        __shared__ int slast;
        if (tid == 0) {
            __threadfence();           // release: publish this block's Df rows
            slast = (atomicAdd(&lncnt[tm], 1) == tilesN - 1) ? 1 : 0;
        }
        __syncthreads();
        if (slast) {
            __threadfence();           // acquire: see all 8 blocks' Df rows
            int lane2 = tid & 63, wv = tid >> 6;
            for (int rr = wv; rr < 64; rr += 4) {
                int row = row0 + rr;
                const float* xr = Df + (size_t)row * Nn + lane2 * 8;
                floatx4 va = *(const floatx4*)(xr);
                floatx4 vb = *(const floatx4*)(xr + 4);
                float ssum = va[0]+va[1]+va[2]+va[3]+vb[0]+vb[1]+vb[2]+vb[3];
                #pragma unroll
                for (int off = 32; off; off >>= 1) ssum += __shfl_xor(ssum, off, 64);
                float mu = ssum * (1.f / 512.f);
                float dd[8];
                dd[0]=va[0]-mu; dd[1]=va[1]-mu; dd[2]=va[2]-mu; dd[3]=va[3]-mu;
                dd[4]=vb[0]-mu; dd[5]=vb[1]-mu; dd[6]=vb[2]-mu; dd[7]=vb[3]-mu;
                float q = dd[0]*dd[0]+dd[1]*dd[1]+dd[2]*dd[2]+dd[3]*dd[3]
                        + dd[4]*dd[4]+dd[5]*dd[5]+dd[6]*dd[6]+dd[7]*dd[7];
                #pragma unroll
                for (int off = 32; off; off >>= 1) q += __shfl_xor(q, off, 64);
                float rstd = 1.f / sqrtf(q * (1.f / 512.f) + 1e-5f);
                float y[8];
                #pragma unroll
                for (int jj = 0; jj < 8; jj++)
                    y[jj] = dd[jj] * rstd * ldin(lng, lnoff + lane2*8 + jj, isf32)
                          + ldin(lnb, lnoff + lane2*8 + jj, isf32);
                floatx4 o0 = {y[0], y[1], y[2], y[3]}, o1 = {y[4], y[5], y[6], y[7]};
                *(floatx4*)(lndst + (size_t)row * HID + lane2*8)     = o0;
                *(floatx4*)(lndst + (size_t)row * HID + lane2*8 + 4) = o1;
                short8 ob;
                #pragma unroll
                for (int jj = 0; jj < 8; jj++) ob[jj] = (short)f2bf(y[jj]);
                *(short8*)(lndstb + (size_t)row * HID + lane2*8) = ob;
            }
        }
    }
}

// MFMA attention: one (b,h) per blockIdx.x, row-half per blockIdx.y.
__global__ __launch_bounds__(128) void attn_mfma(
    const unsigned short* __restrict__ qkvb, unsigned short* __restrict__ aob)
{
    __shared__ unsigned short Vt[64 * VSTR];
    __shared__ unsigned short Pb[64 * VSTR];
    int bh = blockIdx.x;
    int b = bh >> 3, h = bh & 7;
    int rowhalf = blockIdx.y;
    int tid = threadIdx.x;
    int w = tid >> 6, lane = tid & 63;
    int quad = lane >> 4, l16 = lane & 15;
    size_t qbase = (size_t)(b * S_) * 1536 + h * DHEAD;

    for (int i = tid; i < S_ * DHEAD; i += 128) {
        int key = i >> 6, dcol = i & 63;
        Vt[dcol * VSTR + key] = qkvb[qbase + (size_t)key * 1536 + 1024 + dcol];
    }
    __syncthreads();

    int qrow0 = rowhalf * 64 + w * 32;
    short8 aQ[2][2];
    #pragma unroll
    for (int mt = 0; mt < 2; mt++)
        #pragma unroll
        for (int kc = 0; kc < 2; kc++)
            aQ[mt][kc] = *(const short8*)&qkvb[qbase + (size_t)(qrow0 + mt*16 + l16) * 1536 + kc*32 + quad*8];

    floatx4 sacc[2][8];
    #pragma unroll
    for (int mt = 0; mt < 2; mt++)
        #pragma unroll
        for (int nt = 0; nt < 8; nt++)
            sacc[mt][nt] = (floatx4){0.f, 0.f, 0.f, 0.f};

    #pragma unroll
    for (int nt = 0; nt < 8; nt++) {
        const unsigned short* kp = &qkvb[qbase + (size_t)(nt*16 + l16) * 1536 + 512 + quad*8];
        short8 bK0 = *(const short8*)kp;
        short8 bK1 = *(const short8*)(kp + 32);
        #pragma unroll
        for (int mt = 0; mt < 2; mt++) {
            sacc[mt][nt] = __builtin_amdgcn_mfma_f32_16x16x32_bf16(aQ[mt][0], bK0, sacc[mt][nt], 0, 0, 0);
            sacc[mt][nt] = __builtin_amdgcn_mfma_f32_16x16x32_bf16(aQ[mt][1], bK1, sacc[mt][nt], 0, 0, 0);
        }
    }

    #pragma unroll
    for (int mt = 0; mt < 2; mt++)
        #pragma unroll
        for (int reg = 0; reg < 4; reg++) {
            float v[8];
            float m = -3.4e38f;
            #pragma unroll
            for (int nt = 0; nt < 8; nt++) { v[nt] = sacc[mt][nt][reg] * 0.125f; m = fmaxf(m, v[nt]); }
            #pragma unroll
            for (int off = 1; off <= 8; off <<= 1) m = fmaxf(m, __shfl_xor(m, off, 64));
            float sum = 0.f;
            #pragma unroll
            for (int nt = 0; nt < 8; nt++) { v[nt] = expf(v[nt] - m); sum += v[nt]; }
            #pragma unroll
            for (int off = 1; off <= 8; off <<= 1) sum += __shfl_xor(sum, off, 64);
            float inv = 1.f / sum;
            int lr = w*32 + mt*16 + quad*4 + reg;
            #pragma unroll
            for (int nt = 0; nt < 8; nt++)
                Pb[lr * VSTR + nt*16 + l16] = f2bf(v[nt] * inv);
        }
    __syncthreads();

    #pragma unroll
    for (int mt = 0; mt < 2; mt++) {
        short8 aP[4];
        #pragma unroll
        for (int kt = 0; kt < 4; kt++)
            aP[kt] = *(const short8*)&Pb[(w*32 + mt*16 + l16) * VSTR + kt*32 + quad*8];
        #pragma unroll
        for (int nt = 0; nt < 4; nt++) {
            floatx4 o = (floatx4){0.f, 0.f, 0.f, 0.f};
            #pragma unroll
            for (int kt = 0; kt < 4; kt++) {
                short8 bV = *(const short8*)&Vt[(nt*16 + l16) * VSTR + kt*32 + quad*8];
                o = __builtin_amdgcn_mfma_f32_16x16x32_bf16(aP[kt], bV, o, 0, 0, 0);
            }
            #pragma unroll
            for (int reg = 0; reg < 4; reg++) {
                int qrow = qrow0 + mt*16 + quad*4 + reg;
                aob[(size_t)(b*S_ + qrow) * HID + h*DHEAD + nt*16 + l16] = f2bf(o[reg]);
            }
        }
    }
}

extern "C" void kernel_launch(void* const* d_in, const int* in_sizes, int n_in,
                              void* d_out, int out_size, void* d_ws, size_t ws_size,
                              hipStream_t stream)
{
    const void* x_lhand = d_in[0];
    const void* x_rhand = d_in[1];
    const void* j_lhand = d_in[2];
    const void* j_rhand = d_in[3];
    const void* m_contact = d_in[4];
    const void* x_obj = d_in[5];
    const void* point_cloud = d_in[6];
    const void* fc_lw = d_in[7];
    const void* fc_lb = d_in[8];
    const void* fc_rw = d_in[9];
    const void* fc_rb = d_in[10];
    const void* out_lw = d_in[11];
    const void* out_lb = d_in[12];
    const void* out_rw = d_in[13];
    const void* out_rb = d_in[14];
    const void* Wqkv = d_in[15];
    const void* bqkv = d_in[16];
    const void* Wo   = d_in[17];
    const void* bo   = d_in[18];
    const void* W1   = d_in[19];
    const void* b1f  = d_in[20];
    const void* W2   = d_in[21];
    const void* b2fp = d_in[22];
    const void* ln1g = d_in[23];
    const void* ln1b = d_in[24];
    const void* ln2g = d_in[25];
    const void* ln2b = d_in[26];

    float* ws = (float*)d_ws;
    int* dtf = (int*)d_ws;
    int* lncnt = (int*)(ws + F_CNT);
    float* x     = ws + F_X;
    float* tmp   = ws + F_TMP;
    float* h     = ws + F_H;
    unsigned short* qkvb = (unsigned short*)(ws + F_QKV);
    unsigned short* wb   = (unsigned short*)(ws + WB_F);
    unsigned short* catl = wb + U_CATL;
    unsigned short* catr = wb + U_CATR;
    unsigned short* xb   = wb + U_XB;
    unsigned short* aob  = wb + U_AOB;
    unsigned short* hb   = wb + U_HB;
    unsigned short* ffb  = wb + U_FFB;

    PrepP pp;
    pp.x_l = x_lhand; pp.x_r = x_rhand; pp.j_l = j_lhand; pp.j_r = j_rhand;
    pp.mc = m_contact; pp.x_obj = x_obj; pp.pc = point_cloud;
    pp.fc_lw = fc_lw; pp.fc_rw = fc_rw; pp.Wqkv = Wqkv; pp.Wo = Wo;
    pp.W1 = W1; pp.W2 = W2; pp.out_lw = out_lw; pp.out_rw = out_rw;
    pp.wb = wb; pp.catl = catl; pp.catr = catr; pp.dtf = dtf; pp.lncnt = lncnt;
    prep_all<<<PREP_UNITS, 256, 0, stream>>>(pp);

    // fc both hands in one dispatch: 2 x (16x8) blocks; PE fused
    gemm_ks<<<256, 256, 0, stream>>>(catl, catr, CATP, wb, W_FCL, W_FCR, 128, HID,
                                     fc_lb, fc_rb, 0, nullptr, x, xb, 0, 1, 8,
                                     nullptr, nullptr, 0, nullptr, nullptr, nullptr, dtf);

    for (int i = 0; i < NLAY; i++) {
        size_t oWq = (size_t)W_QKV + (size_t)i * 1536 * HID, obq = (size_t)i * 1536;
        size_t oWo = (size_t)W_WO + (size_t)i * HID * HID,   obo = (size_t)i * HID;
        size_t oW1 = (size_t)W_W1 + (size_t)i * 2048 * HID,  ob1 = (size_t)i * 2048;
        size_t oW2 = (size_t)W_W2 + (size_t)i * HID * 2048,  ob2 = (size_t)i * HID;
        size_t oln = (size_t)i * HID;

        // qkv: bf16 output only (consumed by MFMA attention)
        gemm_ks<<<768, 256, 0, stream>>>(xb, nullptr, HID, wb, oWq, 0, 0, 1536,
                                         bqkv, nullptr, obq, nullptr, nullptr, qkvb, 0, 0, 24,
                                         nullptr, nullptr, 0, nullptr, nullptr, nullptr, dtf);

        attn_mfma<<<dim3(B_ * NHEAD, 2), 128, 0, stream>>>(qkvb, aob);

        // Wo + resid(x) -> tmp; fused ln1(tmp) -> h,hb (counter set 2i)
        gemm_ks<<<256, 256, 0, stream>>>(aob, nullptr, HID, wb, oWo, 0, 0, HID,
                                         bo, nullptr, obo, x, tmp, nullptr, 0, 0, 8,
                                         ln1g, ln1b, oln, h, hb, lncnt + (2*i)*32, dtf);

        gemm_ks<<<1024, 256, 0, stream>>>(hb, nullptr, HID, wb, oW1, 0, 0, 2048,
                                          b1f, nullptr, ob1, nullptr, nullptr, ffb, 1, 0, 32,
                                          nullptr, nullptr, 0, nullptr, nullptr, nullptr, dtf);

        // W2 + resid(h) -> tmp; fused ln2(tmp) -> x,xb (counter set 2i+1)
        gemm_ks<<<256, 256, 0, stream>>>(ffb, nullptr, 2048, wb, oW2, 0, 0, HID,
                                         b2fp, nullptr, ob2, h, tmp, nullptr, 0, 0, 8,
                                         ln2g, ln2b, oln, x, xb, lncnt + (2*i+1)*32, dtf);
    }

    // out projection: all tokens x Wcomb[256][512], parity epilogue
    gemm_ks<<<128, 256, 0, stream>>>(xb, nullptr, HID, wb, W_OUT, 0, 0, 256,
                                     out_lb, out_rb, 0, nullptr, (float*)d_out, nullptr, 0, 3, 4,
                                     nullptr, nullptr, 0, nullptr, nullptr, nullptr, dtf);
}

// Round 10
// 701.898 us; speedup vs baseline: 4.0840x; 1.5264x over previous
//
#include <hip/hip_runtime.h>
#include <hip/hip_bf16.h>

typedef __hip_bfloat16 bf16;
typedef __attribute__((ext_vector_type(8))) short short8;
typedef __attribute__((ext_vector_type(4))) float floatx4;

#define B_    16
#define L_    64
#define N_    1024
#define HANDD 99
#define Jn    21
#define HID   512
#define NLAY  4
#define NHEAD 8
#define DHEAD 64
#define CATD  2273
#define CATP  2304
#define S_    128
#define T_    2048

// float workspace offsets
#define F_X     16
#define F_TMP   6291472
#define F_H     7340048
#define WB_F    8388624
// ushort offsets from wb
#define W_FCL   0
#define W_FCR   1179648
#define W_QKV   2359296
#define W_WO    5505024
#define W_W1    6553600
#define W_W2    10747904
#define U_CATL  14942208
#define U_CATR  17301504
#define U_XB    19660800
#define U_AOB   20709376
#define U_HB    21757952
#define W_OUT   22806528
#define U_FFB   U_CATL   // alias: cat buffers dead after fc

#define RSTR 68
#define VSTR 136

// prep_all unit space
#define PC_UNITS 2048      // (b,l) x hand
#define NW_UNITS 3680      // transpose tiles

static __device__ __forceinline__ float b2f(bf16 x) { return __bfloat162float(x); }
static __device__ __forceinline__ float ldin(const void* p, size_t i, int isf32) {
    return isf32 ? ((const float*)p)[i] : b2f(((const bf16*)p)[i]);
}
static __device__ __forceinline__ unsigned short f2bf(float f) {
    unsigned int u = __float_as_uint(f);
    unsigned int r = (u + 0x7fffu + ((u >> 16) & 1u)) >> 16;
    return (unsigned short)r;
}

__global__ __launch_bounds__(256) void detect_kernel(const void* mc, int* flag)
{
    __shared__ int sbad;
    int tid = threadIdx.x;
    if (tid == 0) sbad = 0;
    __syncthreads();
    int bad = 0;
    for (int i = tid; i < 16384; i += 256) {
        float v = b2f(((const bf16*)mc)[i]);
        if (!(v >= -0.02f && v <= 1.02f)) bad = 1;
    }
    if (bad) atomicOr(&sbad, 1);
    __syncthreads();
    if (tid == 0) flag[0] = sbad ? 1 : 0;
}

// ---- merged prep: pctcat (hand-split) + all weight transposes, one dispatch ----
struct PrepP {
    const void *x_l, *x_r, *j_l, *j_r, *mc, *x_obj, *pc;
    const void *fc_lw, *fc_rw, *Wqkv, *Wo, *W1, *W2, *out_lw, *out_rw;
    unsigned short *wb, *catl, *catr;
    const int* dtf;
};

// one (b,l,hand): pc transform + feature row + NN-contact for 21 joints
static __device__ void pctcat_half(int bl, int hand, const PrepP& P, int isf32,
                                   char* smemc)
{
    float* pcl  = (float*)smemc;    // N_*3
    float* pcnl = pcl + N_ * 3;     // N_ (|p|^2)
    int b = bl >> 6;
    int tid = threadIdx.x;

    size_t xo = (size_t)bl * 10;
    float t0 = ldin(P.x_obj, xo+0, isf32), t1 = ldin(P.x_obj, xo+1, isf32), t2 = ldin(P.x_obj, xo+2, isf32);
    float a1x = ldin(P.x_obj, xo+3, isf32), a1y = ldin(P.x_obj, xo+4, isf32), a1z = ldin(P.x_obj, xo+5, isf32);
    float a2x = ldin(P.x_obj, xo+6, isf32), a2y = ldin(P.x_obj, xo+7, isf32), a2z = ldin(P.x_obj, xo+8, isf32);
    float n1 = sqrtf(a1x*a1x + a1y*a1y + a1z*a1z);
    float b1x = a1x / n1, b1y = a1y / n1, b1z = a1z / n1;
    float d = b1x*a2x + b1y*a2y + b1z*a2z;
    float c2x = a2x - d*b1x, c2y = a2y - d*b1y, c2z = a2z - d*b1z;
    float n2 = sqrtf(c2x*c2x + c2y*c2y + c2z*c2z);
    float b2x = c2x / n2, b2y = c2y / n2, b2z = c2z / n2;
    float b3x = b1y*b2z - b1z*b2y;
    float b3y = b1z*b2x - b1x*b2z;
    float b3z = b1x*b2y - b1y*b2x;

    size_t pcb = (size_t)b * N_ * 3;
    for (int n = tid; n < N_; n += 256) {
        float p0 = ldin(P.pc, pcb + n*3+0, isf32);
        float p1 = ldin(P.pc, pcb + n*3+1, isf32);
        float p2 = ldin(P.pc, pcb + n*3+2, isf32);
        float q0 = b1x*p0 + b2x*p1 + b3x*p2 + t0;
        float q1 = b1y*p0 + b2y*p1 + b3y*p2 + t1;
        float q2 = b1z*p0 + b2z*p1 + b3z*p2 + t2;
        pcl[n*3+0] = q0; pcl[n*3+1] = q1; pcl[n*3+2] = q2;
        pcnl[n] = q0*q0 + q1*q1 + q2*q2;
    }
    __syncthreads();

    const void* xh = hand ? P.x_r : P.x_l;
    const void* jh = hand ? P.j_r : P.j_l;
    unsigned short* row = (hand ? P.catr : P.catl) + (size_t)bl * CATP;
    for (int c = tid; c < HANDD; c += 256)  row[c]        = f2bf(ldin(xh, (size_t)bl*HANDD + c, isf32));
    for (int c = tid; c < 63;    c += 256)  row[99 + c]   = f2bf(ldin(jh, (size_t)bl*63 + c, isf32));
    for (int c = tid; c < N_;    c += 256)  row[162 + c]  = f2bf(ldin(P.mc, (size_t)b*N_ + c, isf32));
    for (int c = tid; c < N_;    c += 256)  row[1186 + c] = f2bf(sqrtf(pcnl[c]));
    for (int c = CATD + tid; c < CATP; c += 256) row[c] = 0;

    int wave = tid >> 6, lane = tid & 63;
    for (int j = wave; j < Jn; j += 4) {
        float jx = ldin(jh, (size_t)bl*63 + j*3 + 0, isf32);
        float jy = ldin(jh, (size_t)bl*63 + j*3 + 1, isf32);
        float jz = ldin(jh, (size_t)bl*63 + j*3 + 2, isf32);
        float m2x = -2.f * jx, m2y = -2.f * jy, m2z = -2.f * jz;
        float best = 3.4e38f; int bidx = 0x7fffffff;
        for (int n = lane; n < N_; n += 64) {
            float p0 = pcl[n*3+0], p1 = pcl[n*3+1], p2 = pcl[n*3+2];
            float d2 = fmaf(m2x, p0, fmaf(m2y, p1, fmaf(m2z, p2, pcnl[n])));
            if (d2 < best) { best = d2; bidx = n; }
        }
        for (int off = 32; off; off >>= 1) {
            float ob = __shfl_down(best, off, 64);
            int   oi = __shfl_down(bidx, off, 64);
            if (ob < best || (ob == best && oi < bidx)) { best = ob; bidx = oi; }
        }
        bidx = __shfl(bidx, 0, 64);
        if (lane < 3) {
            float jc = (lane == 0) ? jx : ((lane == 1) ? jy : jz);
            float cc = pcl[bidx*3 + lane];
            float dd = jc - cc;
            row[2210 + j*3 + lane] = f2bf(expf(-50.f * dd * dd));
        }
    }
}

// RACE NOTE (transpose): write guarded by n < NnB. out_lw/out_rw regions abut
// at row 99 (not 64-aligned); unguarded pad writes from the out_lw tiles would
// race with out_rw's real rows 99..127 inside this single dispatch.
__global__ __launch_bounds__(256) void prep_all(PrepP P)
{
    __shared__ __attribute__((aligned(16))) char smem[16640];
    int isf32 = P.dtf[0];
    int u = blockIdx.x;

    if (u < PC_UNITS) {                 // pctcat: (b,l) x hand
        pctcat_half(u >> 1, u & 1, P, isf32, smem);
        return;
    }
    u -= PC_UNITS;
    if (u == NW_UNITS) {                // zero Wcomb rows 198..255 (read, discarded)
        unsigned short* wz = P.wb + W_OUT + (size_t)(2 * HANDD) * HID;
        for (int idx = threadIdx.x; idx < (256 - 2 * HANDD) * HID; idx += 256)
            wz[idx] = 0;
        return;
    }

    float (*tile)[65] = (float(*)[65])smem;
    const void* src; unsigned short* dst;
    int K, Nn, NnB, Kpad, gx; size_t soff = 0, doff = 0;
    if (u < 576) {
        int hh = u >= 288; if (hh) u -= 288;
        src = hh ? P.fc_rw : P.fc_lw; dst = P.wb + (hh ? W_FCR : W_FCL);
        K = CATD; Nn = HID; NnB = HID; Kpad = CATP; gx = 8;
    } else if (u < 1344) {
        int r = u - 576; int z = r / 192; u = r % 192;
        src = P.Wqkv; soff = (size_t)z * HID * 1536;
        dst = P.wb + W_QKV; doff = (size_t)z * 1536 * HID;
        K = HID; Nn = 1536; NnB = 1536; Kpad = HID; gx = 24;
    } else if (u < 1600) {
        int r = u - 1344; int z = r / 64; u = r % 64;
        src = P.Wo; soff = (size_t)z * HID * HID;
        dst = P.wb + W_WO; doff = (size_t)z * HID * HID;
        K = HID; Nn = HID; NnB = HID; Kpad = HID; gx = 8;
    } else if (u < 2624) {
        int r = u - 1600; int z = r / 256; u = r % 256;
        src = P.W1; soff = (size_t)z * HID * 2048;
        dst = P.wb + W_W1; doff = (size_t)z * 2048 * HID;
        K = HID; Nn = 2048; NnB = 2048; Kpad = HID; gx = 32;
    } else if (u < 3648) {
        int r = u - 2624; int z = r / 256; u = r % 256;
        src = P.W2; soff = (size_t)z * 2048 * HID;
        dst = P.wb + W_W2; doff = (size_t)z * HID * 2048;
        K = 2048; Nn = HID; NnB = HID; Kpad = 2048; gx = 8;
    } else {
        int r = u - 3648; int hh = r >= 16; if (hh) r -= 16;
        src = hh ? P.out_rw : P.out_lw;
        dst = P.wb + W_OUT + (hh ? (size_t)HANDD * HID : 0);
        K = HID; Nn = HANDD; NnB = HANDD; Kpad = HID; gx = 2; u = r;
    }
    int n0 = (u % gx) * 64, k0 = (u / gx) * 64;
    int a = threadIdx.x & 63, bq = threadIdx.x >> 6;
    for (int r = bq; r < 64; r += 4) {
        int k = k0 + r, n = n0 + a;
        float v = (k < K && n < NnB) ? ldin(src, soff + (size_t)k * Nn + n, isf32) : 0.f;
        tile[r][a] = v;
    }
    __syncthreads();
    for (int r = bq; r < 64; r += 4) {
        int n = n0 + r;
        if (n < NnB)
            dst[doff + (size_t)n * Kpad + k0 + a] = f2bf(tile[a][r]);
    }
}

// K-split MFMA GEMM: one 64x64 tile per block, 4 waves each take K/4,
// LDS tree-reduce in TWO 32-row stages (34.8KB LDS). rowmap: 0 plain,
// 1/2 fc scatter + fused PE, 3 out-proj parity store. halfgrid: blocks >=
// halfgrid use Ab2/wtoff2/bias2 (rowmap 2).
__global__ __launch_bounds__(256) void gemm_ks(
    const unsigned short* __restrict__ Ab, const unsigned short* __restrict__ Ab2,
    int K,
    const unsigned short* __restrict__ Wt, size_t wtoff, size_t wtoff2, int halfgrid,
    int Nn,
    const void* __restrict__ bias, const void* __restrict__ bias2, size_t boff,
    const float* __restrict__ resid,
    float* __restrict__ Df, unsigned short* __restrict__ Db,
    int relu, int rowmap, int tilesN, const int* __restrict__ dtf)
{
    __shared__ float red[4][32 * RSTR];
    int blk = blockIdx.x;
    if (halfgrid && blk >= halfgrid) {
        blk -= halfgrid; Ab = Ab2; wtoff = wtoff2; bias = bias2; rowmap = 2;
    }
    int tid = threadIdx.x;
    int wave = tid >> 6, lane = tid & 63;
    int quad = lane >> 4, l16 = lane & 15;
    int tm = blk / tilesN, tn = blk - tm * tilesN;
    int row0 = tm << 6, col0 = tn << 6;
    int Ks = K >> 2;
    int ks0 = wave * Ks;

    const unsigned short* Ap = Ab + (size_t)(row0 + l16) * K + ks0 + quad * 8;
    const unsigned short* Bp = Wt + wtoff + (size_t)(col0 + l16) * K + ks0 + quad * 8;
    size_t astep = (size_t)16 * K;

    floatx4 acc[4][4];
    #pragma unroll
    for (int i = 0; i < 4; i++)
        #pragma unroll
        for (int j = 0; j < 4; j++)
            acc[i][j] = (floatx4){0.f, 0.f, 0.f, 0.f};

    for (int k = 0; k < Ks; k += 32) {
        short8 af[4], bf[4];
        #pragma unroll
        for (int i = 0; i < 4; i++) {
            af[i] = *(const short8*)(Ap + i * astep + k);
            bf[i] = *(const short8*)(Bp + i * astep + k);
        }
        #pragma unroll
        for (int mi = 0; mi < 4; mi++)
            #pragma unroll
            for (int ni = 0; ni < 4; ni++)
                acc[mi][ni] = __builtin_amdgcn_mfma_f32_16x16x32_bf16(
                    af[mi], bf[ni], acc[mi][ni], 0, 0, 0);
    }

    // per-column epilogue constants
    int isf32 = dtf[0];
    int cc = tid & 63;
    int c = col0 + cc;
    float bv;
    if (rowmap == 3)
        bv = (c < HANDD) ? ldin(bias, c, isf32)
           : ((c < 2 * HANDD) ? ldin(bias2, c - HANDD, isf32) : 0.f);
    else
        bv = bias ? ldin(bias, boff + c, isf32) : 0.f;
    float pe_div = 0.f, pa = 0.f;
    if (rowmap == 1 || rowmap == 2) {
        int ci = c & ~1;
        pe_div = expf((float)ci * (-logf(10000.f) / (float)HID));
        int hand = rowmap - 1;
        pa = (c & 1) ? cosf((float)hand * pe_div) : sinf((float)hand * pe_div);
    }
    int rbase = tid >> 6;

    #pragma unroll
    for (int s = 0; s < 2; s++) {
        #pragma unroll
        for (int mi2 = 0; mi2 < 2; mi2++) {
            int mi = s * 2 + mi2;
            #pragma unroll
            for (int ni = 0; ni < 4; ni++)
                #pragma unroll
                for (int reg = 0; reg < 4; reg++) {
                    int r = mi2 * 16 + quad * 4 + reg;   // 0..31
                    int col = ni * 16 + l16;
                    red[wave][r * RSTR + col] = acc[mi][ni][reg];
                }
        }
        __syncthreads();

        #pragma unroll
        for (int j = 0; j < 8; j++) {
            int rr = rbase + (j << 2);   // 0..31
            int idx = rr * RSTR + cc;
            float v = red[0][idx] + red[1][idx] + red[2][idx] + red[3][idx] + bv;
            int r = row0 + s * 32 + rr;
            if (resid) v += resid[(size_t)r * Nn + c];
            if (relu)  v = fmaxf(v, 0.f);
            if (rowmap == 3) {
                int hand = r & 1;
                int l = (r >> 1) & 63, bb = r >> 7;
                if (hand == 0 && c < HANDD) {
                    size_t oi = ((size_t)bb * 64 + l) * HANDD + c;
                    if (isf32) ((float*)Df)[oi] = v;
                    else       ((bf16*)Df)[oi]  = __float2bfloat16(v);
                } else if (hand == 1 && c >= HANDD && c < 2 * HANDD) {
                    size_t oi = (size_t)B_ * L_ * HANDD + ((size_t)bb * 64 + l) * HANDD + (c - HANDD);
                    if (isf32) ((float*)Df)[oi] = v;
                    else       ((bf16*)Df)[oi]  = __float2bfloat16(v);
                }
            } else {
                int orow = r;
                if (rowmap) {
                    int bb = r >> 6, ll = r & 63;
                    orow = bb * S_ + 2 * ll + (rowmap - 1);
                    float pf = (c & 1) ? cosf((float)ll * pe_div) : sinf((float)ll * pe_div);
                    v += pf + pa;
                }
                if (Df) Df[(size_t)orow * Nn + c] = v;
                if (Db) Db[(size_t)orow * Nn + c] = f2bf(v);
            }
        }
        if (s == 0) __syncthreads();   // red reused by stage 1
    }
}

// ---- fused qkv-projection + attention: one block per (b,h), 256 threads ----
// Wave w MFMAs token rows w*32..w*32+31 x {Q,K,V} head slices (K=512) from
// xb and the transposed Wqkv; Q/K row-major + V^T into LDS; then runs the
// (r7-verified) 256-thread attention body sourcing Q/K from LDS.
// LDS: Ql[128][68] + Kl[128][68] (34816B, aliased later by Pb[128][136]),
// Vt[64][136] (17408B). Total 52224B.
__global__ __launch_bounds__(256) void qkvattn(
    const unsigned short* __restrict__ xb,
    const unsigned short* __restrict__ Wt, size_t oWq,
    const void* __restrict__ bqkv, size_t obq,
    unsigned short* __restrict__ aob, const int* __restrict__ dtf)
{
    __shared__ __attribute__((aligned(16))) unsigned short smem[26112];
    unsigned short* Ql = smem;            // [128][68]
    unsigned short* Kl = smem + 8704;     // [128][68]
    unsigned short* Pb = smem;            // [128][VSTR] (alias Ql+Kl; guarded)
    unsigned short* Vt = smem + 17408;    // [64][VSTR], Vt[dcol*VSTR+key]
    int isf32 = dtf[0];
    int bh = blockIdx.x;
    int b = bh >> 3, h = bh & 7;
    int tid = threadIdx.x;
    int w = tid >> 6, lane = tid & 63;
    int quad = lane >> 4, l16 = lane & 15;

    // --- QKV projection: this wave owns token rows w*32 .. w*32+31 ---
    const unsigned short* Ap0 = xb + (size_t)(b * S_ + w * 32 + l16) * HID + quad * 8;
    #pragma unroll
    for (int o = 0; o < 3; o++) {
        int outbase = o * 512 + h * DHEAD;
        const unsigned short* Bp = Wt + oWq + (size_t)(outbase + l16) * HID + quad * 8;
        floatx4 acc[2][4];
        #pragma unroll
        for (int mi = 0; mi < 2; mi++)
            #pragma unroll
            for (int ni = 0; ni < 4; ni++)
                acc[mi][ni] = (floatx4){0.f, 0.f, 0.f, 0.f};
        for (int k = 0; k < HID; k += 32) {
            short8 af[2], bf[4];
            #pragma unroll
            for (int mi = 0; mi < 2; mi++)
                af[mi] = *(const short8*)(Ap0 + (size_t)mi * 16 * HID + k);
            #pragma unroll
            for (int ni = 0; ni < 4; ni++)
                bf[ni] = *(const short8*)(Bp + (size_t)ni * 16 * HID + k);
            #pragma unroll
            for (int mi = 0; mi < 2; mi++)
                #pragma unroll
                for (int ni = 0; ni < 4; ni++)
                    acc[mi][ni] = __builtin_amdgcn_mfma_f32_16x16x32_bf16(
                        af[mi], bf[ni], acc[mi][ni], 0, 0, 0);
        }
        #pragma unroll
        for (int ni = 0; ni < 4; ni++) {
            float bv = ldin(bqkv, obq + outbase + ni * 16 + l16, isf32);
            #pragma unroll
            for (int mi = 0; mi < 2; mi++)
                #pragma unroll
                for (int reg = 0; reg < 4; reg++) {
                    int row = w * 32 + mi * 16 + quad * 4 + reg;   // token 0..127
                    int col = ni * 16 + l16;                        // 0..63
                    unsigned short hv = f2bf(acc[mi][ni][reg] + bv);
                    if (o == 0)      Ql[row * 68 + col] = hv;
                    else if (o == 1) Kl[row * 68 + col] = hv;
                    else             Vt[col * VSTR + row] = hv;
                }
        }
    }
    __syncthreads();   // K/V rows from other waves now visible

    // --- QK^T (Q rows are this wave's own; K rows cross-wave) ---
    int qrow0 = w * 32;
    short8 aQ[2][2];
    #pragma unroll
    for (int mt = 0; mt < 2; mt++)
        #pragma unroll
        for (int kc = 0; kc < 2; kc++)
            aQ[mt][kc] = *(const short8*)&Ql[(qrow0 + mt*16 + l16) * 68 + kc*32 + quad*8];

    floatx4 sacc[2][8];
    #pragma unroll
    for (int mt = 0; mt < 2; mt++)
        #pragma unroll
        for (int nt = 0; nt < 8; nt++)
            sacc[mt][nt] = (floatx4){0.f, 0.f, 0.f, 0.f};

    #pragma unroll
    for (int nt = 0; nt < 8; nt++) {
        const unsigned short* kp = &Kl[(nt*16 + l16) * 68 + quad*8];
        short8 bK0 = *(const short8*)kp;
        short8 bK1 = *(const short8*)(kp + 32);
        #pragma unroll
        for (int mt = 0; mt < 2; mt++) {
            sacc[mt][nt] = __builtin_amdgcn_mfma_f32_16x16x32_bf16(aQ[mt][0], bK0, sacc[mt][nt], 0, 0, 0);
            sacc[mt][nt] = __builtin_amdgcn_mfma_f32_16x16x32_bf16(aQ[mt][1], bK1, sacc[mt][nt], 0, 0, 0);
        }
    }
    __syncthreads();   // ALIAS GUARD: all waves done reading Ql/Kl before Pb writes

    // --- softmax (r5/r7-verified body) ---
    #pragma unroll
    for (int mt = 0; mt < 2; mt++)
        #pragma unroll
        for (int reg = 0; reg < 4; reg++) {
            float v[8];
            float m = -3.4e38f;
            #pragma unroll
            for (int nt = 0; nt < 8; nt++) { v[nt] = sacc[mt][nt][reg] * 0.125f; m = fmaxf(m, v[nt]); }
            #pragma unroll
            for (int off = 1; off <= 8; off <<= 1) m = fmaxf(m, __shfl_xor(m, off, 64));
            float sum = 0.f;
            #pragma unroll
            for (int nt = 0; nt < 8; nt++) { v[nt] = expf(v[nt] - m); sum += v[nt]; }
            #pragma unroll
            for (int off = 1; off <= 8; off <<= 1) sum += __shfl_xor(sum, off, 64);
            float inv = 1.f / sum;
            int lr = qrow0 + mt*16 + quad*4 + reg;    // 0..127
            #pragma unroll
            for (int nt = 0; nt < 8; nt++)
                Pb[lr * VSTR + nt*16 + l16] = f2bf(v[nt] * inv);
        }
    __syncthreads();

    // --- PV ---
    #pragma unroll
    for (int mt = 0; mt < 2; mt++) {
        short8 aP[4];
        #pragma unroll
        for (int kt = 0; kt < 4; kt++)
            aP[kt] = *(const short8*)&Pb[(qrow0 + mt*16 + l16) * VSTR + kt*32 + quad*8];
        #pragma unroll
        for (int nt = 0; nt < 4; nt++) {
            floatx4 o = (floatx4){0.f, 0.f, 0.f, 0.f};
            #pragma unroll
            for (int kt = 0; kt < 4; kt++) {
                short8 bV = *(const short8*)&Vt[(nt*16 + l16) * VSTR + kt*32 + quad*8];
                o = __builtin_amdgcn_mfma_f32_16x16x32_bf16(aP[kt], bV, o, 0, 0, 0);
            }
            #pragma unroll
            for (int reg = 0; reg < 4; reg++) {
                int qrow = qrow0 + mt*16 + quad*4 + reg;
                aob[(size_t)(b*S_ + qrow) * HID + h*DHEAD + nt*16 + l16] = f2bf(o[reg]);
            }
        }
    }
}

__global__ __launch_bounds__(256) void ln_kernel(
    const float* __restrict__ src, const void* __restrict__ g,
    const void* __restrict__ bb, size_t goff,
    float* __restrict__ dst, unsigned short* __restrict__ dstb,
    const int* __restrict__ dtf)
{
    int isf32 = dtf[0];
    int t = blockIdx.x;
    const float* x = src + (size_t)t * HID;
    int tid = threadIdx.x, lane = tid & 63, wave = tid >> 6;
    float v0 = x[tid], v1 = x[tid + 256];
    float s = v0 + v1;
    for (int off = 32; off; off >>= 1) s += __shfl_down(s, off, 64);
    __shared__ float wsum[4];
    if (lane == 0) wsum[wave] = s;
    __syncthreads();
    float mu = (wsum[0] + wsum[1] + wsum[2] + wsum[3]) * (1.f / 512.f);
    float d0 = v0 - mu, d1 = v1 - mu;
    float q = d0 * d0 + d1 * d1;
    for (int off = 32; off; off >>= 1) q += __shfl_down(q, off, 64);
    __syncthreads();
    if (lane == 0) wsum[wave] = q;
    __syncthreads();
    float var = (wsum[0] + wsum[1] + wsum[2] + wsum[3]) * (1.f / 512.f);
    float rstd = 1.f / sqrtf(var + 1e-5f);
    float y0 = d0 * rstd * ldin(g, goff + tid, isf32)       + ldin(bb, goff + tid, isf32);
    float y1 = d1 * rstd * ldin(g, goff + tid + 256, isf32) + ldin(bb, goff + tid + 256, isf32);
    if (dst) {
        dst[(size_t)t * HID + tid]       = y0;
        dst[(size_t)t * HID + tid + 256] = y1;
    }
    if (dstb) {
        dstb[(size_t)t * HID + tid]       = f2bf(y0);
        dstb[(size_t)t * HID + tid + 256] = f2bf(y1);
    }
}

extern "C" void kernel_launch(void* const* d_in, const int* in_sizes, int n_in,
                              void* d_out, int out_size, void* d_ws, size_t ws_size,
                              hipStream_t stream)
{
    const void* x_lhand = d_in[0];
    const void* x_rhand = d_in[1];
    const void* j_lhand = d_in[2];
    const void* j_rhand = d_in[3];
    const void* m_contact = d_in[4];
    const void* x_obj = d_in[5];
    const void* point_cloud = d_in[6];
    const void* fc_lw = d_in[7];
    const void* fc_lb = d_in[8];
    const void* fc_rw = d_in[9];
    const void* fc_rb = d_in[10];
    const void* out_lw = d_in[11];
    const void* out_lb = d_in[12];
    const void* out_rw = d_in[13];
    const void* out_rb = d_in[14];
    const void* Wqkv = d_in[15];
    const void* bqkv = d_in[16];
    const void* Wo   = d_in[17];
    const void* bo   = d_in[18];
    const void* W1   = d_in[19];
    const void* b1f  = d_in[20];
    const void* W2   = d_in[21];
    const void* b2fp = d_in[22];
    const void* ln1g = d_in[23];
    const void* ln1b = d_in[24];
    const void* ln2g = d_in[25];
    const void* ln2b = d_in[26];

    float* ws = (float*)d_ws;
    int* dtf = (int*)d_ws;
    float* x     = ws + F_X;
    float* tmp   = ws + F_TMP;
    float* h     = ws + F_H;
    unsigned short* wb   = (unsigned short*)(ws + WB_F);
    unsigned short* catl = wb + U_CATL;
    unsigned short* catr = wb + U_CATR;
    unsigned short* xb   = wb + U_XB;
    unsigned short* aob  = wb + U_AOB;
    unsigned short* hb   = wb + U_HB;
    unsigned short* ffb  = wb + U_FFB;

    detect_kernel<<<1, 256, 0, stream>>>(m_contact, dtf);

    PrepP pp;
    pp.x_l = x_lhand; pp.x_r = x_rhand; pp.j_l = j_lhand; pp.j_r = j_rhand;
    pp.mc = m_contact; pp.x_obj = x_obj; pp.pc = point_cloud;
    pp.fc_lw = fc_lw; pp.fc_rw = fc_rw; pp.Wqkv = Wqkv; pp.Wo = Wo;
    pp.W1 = W1; pp.W2 = W2; pp.out_lw = out_lw; pp.out_rw = out_rw;
    pp.wb = wb; pp.catl = catl; pp.catr = catr; pp.dtf = dtf;
    prep_all<<<PC_UNITS + NW_UNITS + 1, 256, 0, stream>>>(pp);

    // fc both hands in one dispatch: 2 x (16x8) blocks; PE fused
    gemm_ks<<<256, 256, 0, stream>>>(catl, catr, CATP, wb, W_FCL, W_FCR, 128, HID,
                                     fc_lb, fc_rb, 0, nullptr, x, xb, 0, 1, 8, dtf);

    for (int i = 0; i < NLAY; i++) {
        size_t oWq = (size_t)W_QKV + (size_t)i * 1536 * HID, obq = (size_t)i * 1536;
        size_t oWo = (size_t)W_WO + (size_t)i * HID * HID,   obo = (size_t)i * HID;
        size_t oW1 = (size_t)W_W1 + (size_t)i * 2048 * HID,  ob1 = (size_t)i * 2048;
        size_t oW2 = (size_t)W_W2 + (size_t)i * HID * 2048,  ob2 = (size_t)i * HID;
        size_t oln = (size_t)i * HID;

        // fused qkv + attention: one dispatch, no qkvb round-trip
        qkvattn<<<B_ * NHEAD, 256, 0, stream>>>(xb, wb, oWq, bqkv, obq, aob, dtf);

        gemm_ks<<<256, 256, 0, stream>>>(aob, nullptr, HID, wb, oWo, 0, 0, HID,
                                         bo, nullptr, obo, x, tmp, nullptr, 0, 0, 8, dtf);
        ln_kernel<<<T_, 256, 0, stream>>>(tmp, ln1g, ln1b, oln, h, hb, dtf);

        gemm_ks<<<1024, 256, 0, stream>>>(hb, nullptr, HID, wb, oW1, 0, 0, 2048,
                                          b1f, nullptr, ob1, nullptr, nullptr, ffb, 1, 0, 32, dtf);
        gemm_ks<<<256, 256, 0, stream>>>(ffb, nullptr, 2048, wb, oW2, 0, 0, HID,
                                         b2fp, nullptr, ob2, h, tmp, nullptr, 0, 0, 8, dtf);
        ln_kernel<<<T_, 256, 0, stream>>>(tmp, ln2g, ln2b, oln, x, xb, dtf);
    }

    // out projection: all tokens x Wcomb[256][512], parity epilogue
    gemm_ks<<<128, 256, 0, stream>>>(xb, nullptr, HID, wb, W_OUT, 0, 0, 256,
                                     out_lb, out_rb, 0, nullptr, (float*)d_out, nullptr, 0, 3, 4, dtf);
}

// Round 11
// 651.519 us; speedup vs baseline: 4.3997x; 1.0773x over previous
//
#include <hip/hip_runtime.h>
#include <hip/hip_bf16.h>

typedef __hip_bfloat16 bf16;
typedef __attribute__((ext_vector_type(8))) short short8;
typedef __attribute__((ext_vector_type(4))) float floatx4;

#define B_    16
#define L_    64
#define N_    1024
#define HANDD 99
#define Jn    21
#define HID   512
#define NLAY  4
#define NHEAD 8
#define DHEAD 64
#define CATD  2273
#define CATP  2304
#define S_    128
#define T_    2048

// float workspace offsets
#define F_X     16
#define F_QKV   1048592
#define F_TMP   6291472
#define F_H     7340048
#define WB_F    8388624
// ushort offsets from wb
#define W_FCL   0
#define W_FCR   1179648
#define W_QKV   2359296
#define W_WO    5505024
#define W_W1    6553600
#define W_W2    10747904
#define U_CATL  14942208
#define U_CATR  17301504
#define U_XB    19660800
#define U_AOB   20709376
#define U_HB    21757952
#define W_OUT   22806528
#define U_FFB   U_CATL   // alias: cat buffers dead after fc

#define RSTR 68
#define VSTR 136

// prep_all unit space
#define PC_UNITS 2048      // (b,l) x hand
#define NW_UNITS 3680      // transpose tiles

static __device__ __forceinline__ float b2f(bf16 x) { return __bfloat162float(x); }
static __device__ __forceinline__ float ldin(const void* p, size_t i, int isf32) {
    return isf32 ? ((const float*)p)[i] : b2f(((const bf16*)p)[i]);
}
static __device__ __forceinline__ unsigned short f2bf(float f) {
    unsigned int u = __float_as_uint(f);
    unsigned int r = (u + 0x7fffu + ((u >> 16) & 1u)) >> 16;
    return (unsigned short)r;
}

__global__ __launch_bounds__(256) void detect_kernel(const void* mc, int* flag)
{
    __shared__ int sbad;
    int tid = threadIdx.x;
    if (tid == 0) sbad = 0;
    __syncthreads();
    int bad = 0;
    for (int i = tid; i < 16384; i += 256) {
        float v = b2f(((const bf16*)mc)[i]);
        if (!(v >= -0.02f && v <= 1.02f)) bad = 1;
    }
    if (bad) atomicOr(&sbad, 1);
    __syncthreads();
    if (tid == 0) flag[0] = sbad ? 1 : 0;
}

// ---- merged prep: pctcat (hand-split) + all weight transposes, one dispatch ----
struct PrepP {
    const void *x_l, *x_r, *j_l, *j_r, *mc, *x_obj, *pc;
    const void *fc_lw, *fc_rw, *Wqkv, *Wo, *W1, *W2, *out_lw, *out_rw;
    unsigned short *wb, *catl, *catr;
    const int* dtf;
};

// one (b,l,hand): pc transform + feature row + NN-contact for 21 joints
static __device__ void pctcat_half(int bl, int hand, const PrepP& P, int isf32,
                                   char* smemc)
{
    float* pcl  = (float*)smemc;    // N_*3
    float* pcnl = pcl + N_ * 3;     // N_ (|p|^2)
    int b = bl >> 6;
    int tid = threadIdx.x;

    size_t xo = (size_t)bl * 10;
    float t0 = ldin(P.x_obj, xo+0, isf32), t1 = ldin(P.x_obj, xo+1, isf32), t2 = ldin(P.x_obj, xo+2, isf32);
    float a1x = ldin(P.x_obj, xo+3, isf32), a1y = ldin(P.x_obj, xo+4, isf32), a1z = ldin(P.x_obj, xo+5, isf32);
    float a2x = ldin(P.x_obj, xo+6, isf32), a2y = ldin(P.x_obj, xo+7, isf32), a2z = ldin(P.x_obj, xo+8, isf32);
    float n1 = sqrtf(a1x*a1x + a1y*a1y + a1z*a1z);
    float b1x = a1x / n1, b1y = a1y / n1, b1z = a1z / n1;
    float d = b1x*a2x + b1y*a2y + b1z*a2z;
    float c2x = a2x - d*b1x, c2y = a2y - d*b1y, c2z = a2z - d*b1z;
    float n2 = sqrtf(c2x*c2x + c2y*c2y + c2z*c2z);
    float b2x = c2x / n2, b2y = c2y / n2, b2z = c2z / n2;
    float b3x = b1y*b2z - b1z*b2y;
    float b3y = b1z*b2x - b1x*b2z;
    float b3z = b1x*b2y - b1y*b2x;

    size_t pcb = (size_t)b * N_ * 3;
    for (int n = tid; n < N_; n += 256) {
        float p0 = ldin(P.pc, pcb + n*3+0, isf32);
        float p1 = ldin(P.pc, pcb + n*3+1, isf32);
        float p2 = ldin(P.pc, pcb + n*3+2, isf32);
        float q0 = b1x*p0 + b2x*p1 + b3x*p2 + t0;
        float q1 = b1y*p0 + b2y*p1 + b3y*p2 + t1;
        float q2 = b1z*p0 + b2z*p1 + b3z*p2 + t2;
        pcl[n*3+0] = q0; pcl[n*3+1] = q1; pcl[n*3+2] = q2;
        pcnl[n] = q0*q0 + q1*q1 + q2*q2;
    }
    __syncthreads();

    const void* xh = hand ? P.x_r : P.x_l;
    const void* jh = hand ? P.j_r : P.j_l;
    unsigned short* row = (hand ? P.catr : P.catl) + (size_t)bl * CATP;
    if (!isf32) {
        // bf16 inputs: raw ushort copies (f2bf(b2f(x)) == x) — ran clean in r9
        const unsigned short* xs = (const unsigned short*)xh + (size_t)bl * HANDD;
        const unsigned short* js = (const unsigned short*)jh + (size_t)bl * 63;
        const unsigned short* ms = (const unsigned short*)P.mc + (size_t)b * N_;
        for (int c = tid; c < HANDD; c += 256)  row[c]       = xs[c];
        for (int c = tid; c < 63;    c += 256)  row[99 + c]  = js[c];
        for (int c = tid; c < N_;    c += 256)  row[162 + c] = ms[c];
    } else {
        for (int c = tid; c < HANDD; c += 256)  row[c]       = f2bf(ldin(xh, (size_t)bl*HANDD + c, isf32));
        for (int c = tid; c < 63;    c += 256)  row[99 + c]  = f2bf(ldin(jh, (size_t)bl*63 + c, isf32));
        for (int c = tid; c < N_;    c += 256)  row[162 + c] = f2bf(ldin(P.mc, (size_t)b*N_ + c, isf32));
    }
    for (int c = tid; c < N_;    c += 256)  row[1186 + c] = f2bf(sqrtf(pcnl[c]));
    for (int c = CATD + tid; c < CATP; c += 256) row[c] = 0;

    int wave = tid >> 6, lane = tid & 63;
    for (int j = wave; j < Jn; j += 4) {
        float jx = ldin(jh, (size_t)bl*63 + j*3 + 0, isf32);
        float jy = ldin(jh, (size_t)bl*63 + j*3 + 1, isf32);
        float jz = ldin(jh, (size_t)bl*63 + j*3 + 2, isf32);
        float m2x = -2.f * jx, m2y = -2.f * jy, m2z = -2.f * jz;
        float best = 3.4e38f; int bidx = 0x7fffffff;
        for (int n = lane; n < N_; n += 64) {
            float p0 = pcl[n*3+0], p1 = pcl[n*3+1], p2 = pcl[n*3+2];
            float d2 = fmaf(m2x, p0, fmaf(m2y, p1, fmaf(m2z, p2, pcnl[n])));
            if (d2 < best) { best = d2; bidx = n; }
        }
        for (int off = 32; off; off >>= 1) {
            float ob = __shfl_down(best, off, 64);
            int   oi = __shfl_down(bidx, off, 64);
            if (ob < best || (ob == best && oi < bidx)) { best = ob; bidx = oi; }
        }
        bidx = __shfl(bidx, 0, 64);
        if (lane < 3) {
            float jc = (lane == 0) ? jx : ((lane == 1) ? jy : jz);
            float cc = pcl[bidx*3 + lane];
            float dd = jc - cc;
            row[2210 + j*3 + lane] = f2bf(expf(-50.f * dd * dd));
        }
    }
}

// RACE NOTE (transpose): write guarded by n < NnB. out_lw/out_rw regions abut
// at row 99 (not 64-aligned); unguarded pad writes from the out_lw tiles would
// race with out_rw's real rows 99..127 inside this single dispatch.
__global__ __launch_bounds__(256) void prep_all(PrepP P)
{
    __shared__ __attribute__((aligned(16))) char smem[16640];
    int isf32 = P.dtf[0];
    int u = blockIdx.x;

    if (u < PC_UNITS) {                 // pctcat: (b,l) x hand
        pctcat_half(u >> 1, u & 1, P, isf32, smem);
        return;
    }
    u -= PC_UNITS;
    if (u == NW_UNITS) {                // zero Wcomb rows 198..255 (read, discarded)
        unsigned short* wz = P.wb + W_OUT + (size_t)(2 * HANDD) * HID;
        for (int idx = threadIdx.x; idx < (256 - 2 * HANDD) * HID; idx += 256)
            wz[idx] = 0;
        return;
    }

    const void* src; unsigned short* dst;
    int K, Nn, NnB, Kpad, gx; size_t soff = 0, doff = 0;
    if (u < 576) {
        int hh = u >= 288; if (hh) u -= 288;
        src = hh ? P.fc_rw : P.fc_lw; dst = P.wb + (hh ? W_FCR : W_FCL);
        K = CATD; Nn = HID; NnB = HID; Kpad = CATP; gx = 8;
    } else if (u < 1344) {
        int r = u - 576; int z = r / 192; u = r % 192;
        src = P.Wqkv; soff = (size_t)z * HID * 1536;
        dst = P.wb + W_QKV; doff = (size_t)z * 1536 * HID;
        K = HID; Nn = 1536; NnB = 1536; Kpad = HID; gx = 24;
    } else if (u < 1600) {
        int r = u - 1344; int z = r / 64; u = r % 64;
        src = P.Wo; soff = (size_t)z * HID * HID;
        dst = P.wb + W_WO; doff = (size_t)z * HID * HID;
        K = HID; Nn = HID; NnB = HID; Kpad = HID; gx = 8;
    } else if (u < 2624) {
        int r = u - 1600; int z = r / 256; u = r % 256;
        src = P.W1; soff = (size_t)z * HID * 2048;
        dst = P.wb + W_W1; doff = (size_t)z * 2048 * HID;
        K = HID; Nn = 2048; NnB = 2048; Kpad = HID; gx = 32;
    } else if (u < 3648) {
        int r = u - 2624; int z = r / 256; u = r % 256;
        src = P.W2; soff = (size_t)z * 2048 * HID;
        dst = P.wb + W_W2; doff = (size_t)z * HID * 2048;
        K = 2048; Nn = HID; NnB = HID; Kpad = 2048; gx = 8;
    } else {
        int r = u - 3648; int hh = r >= 16; if (hh) r -= 16;
        src = hh ? P.out_rw : P.out_lw;
        dst = P.wb + W_OUT + (hh ? (size_t)HANDD * HID : 0);
        K = HID; Nn = HANDD; NnB = HANDD; Kpad = HID; gx = 2; u = r;
    }
    int n0 = (u % gx) * 64, k0 = (u / gx) * 64;
    int tid = threadIdx.x;

    if (!isf32 && (Nn % 8) == 0) {
        // bf16 fast path (ran clean in r9): raw ushort transpose, short8 IO.
        unsigned short (*tu)[68] = (unsigned short(*)[68])smem;
        const unsigned short* s = (const unsigned short*)src;
        #pragma unroll
        for (int pass = 0; pass < 2; pass++) {
            int r = (tid >> 3) + pass * 32;
            int k = k0 + r;
            int nb = (tid & 7) * 8;
            short8 v = (short8){0,0,0,0,0,0,0,0};
            if (k < K) v = *(const short8*)(s + soff + (size_t)k * Nn + n0 + nb);
            #pragma unroll
            for (int j = 0; j < 8; j++) tu[r][nb + j] = (unsigned short)v[j];
        }
        __syncthreads();
        #pragma unroll
        for (int pass = 0; pass < 2; pass++) {
            int rp = (tid >> 3) + pass * 32;
            int n = n0 + rp;
            int kb = (tid & 7) * 8;
            if (n < NnB) {
                short8 o;
                #pragma unroll
                for (int j = 0; j < 8; j++) o[j] = (short)tu[kb + j][rp];
                *(short8*)(dst + doff + (size_t)n * Kpad + k0 + kb) = o;
            }
        }
    } else {
        // f32 (or Nn%8!=0, e.g. out_lw Nn=99) path: scalar via f32 LDS tile
        float (*tile)[65] = (float(*)[65])smem;
        int a = tid & 63, bq = tid >> 6;
        for (int r = bq; r < 64; r += 4) {
            int k = k0 + r, n = n0 + a;
            float v = (k < K && n < NnB) ? ldin(src, soff + (size_t)k * Nn + n, isf32) : 0.f;
            tile[r][a] = v;
        }
        __syncthreads();
        for (int r = bq; r < 64; r += 4) {
            int n = n0 + r;
            if (n < NnB)
                dst[doff + (size_t)n * Kpad + k0 + a] = f2bf(tile[a][r]);
        }
    }
}

// K-split MFMA GEMM: one 64x64 tile per block, 4 waves each take K/4,
// LDS tree-reduce in TWO 32-row stages (34.8KB LDS). rowmap: 0 plain,
// 1/2 fc scatter + fused PE, 3 out-proj parity store. halfgrid: blocks >=
// halfgrid use Ab2/wtoff2/bias2 (rowmap 2).
__global__ __launch_bounds__(256) void gemm_ks(
    const unsigned short* __restrict__ Ab, const unsigned short* __restrict__ Ab2,
    int K,
    const unsigned short* __restrict__ Wt, size_t wtoff, size_t wtoff2, int halfgrid,
    int Nn,
    const void* __restrict__ bias, const void* __restrict__ bias2, size_t boff,
    const float* __restrict__ resid,
    float* __restrict__ Df, unsigned short* __restrict__ Db,
    int relu, int rowmap, int tilesN, const int* __restrict__ dtf)
{
    __shared__ float red[4][32 * RSTR];
    int blk = blockIdx.x;
    if (halfgrid && blk >= halfgrid) {
        blk -= halfgrid; Ab = Ab2; wtoff = wtoff2; bias = bias2; rowmap = 2;
    }
    int tid = threadIdx.x;
    int wave = tid >> 6, lane = tid & 63;
    int quad = lane >> 4, l16 = lane & 15;
    int tm = blk / tilesN, tn = blk - tm * tilesN;
    int row0 = tm << 6, col0 = tn << 6;
    int Ks = K >> 2;
    int ks0 = wave * Ks;

    const unsigned short* Ap = Ab + (size_t)(row0 + l16) * K + ks0 + quad * 8;
    const unsigned short* Bp = Wt + wtoff + (size_t)(col0 + l16) * K + ks0 + quad * 8;
    size_t astep = (size_t)16 * K;

    floatx4 acc[4][4];
    #pragma unroll
    for (int i = 0; i < 4; i++)
        #pragma unroll
        for (int j = 0; j < 4; j++)
            acc[i][j] = (floatx4){0.f, 0.f, 0.f, 0.f};

    for (int k = 0; k < Ks; k += 32) {
        short8 af[4], bf[4];
        #pragma unroll
        for (int i = 0; i < 4; i++) {
            af[i] = *(const short8*)(Ap + i * astep + k);
            bf[i] = *(const short8*)(Bp + i * astep + k);
        }
        #pragma unroll
        for (int mi = 0; mi < 4; mi++)
            #pragma unroll
            for (int ni = 0; ni < 4; ni++)
                acc[mi][ni] = __builtin_amdgcn_mfma_f32_16x16x32_bf16(
                    af[mi], bf[ni], acc[mi][ni], 0, 0, 0);
    }

    // per-column epilogue constants
    int isf32 = dtf[0];
    int cc = tid & 63;
    int c = col0 + cc;
    float bv;
    if (rowmap == 3)
        bv = (c < HANDD) ? ldin(bias, c, isf32)
           : ((c < 2 * HANDD) ? ldin(bias2, c - HANDD, isf32) : 0.f);
    else
        bv = bias ? ldin(bias, boff + c, isf32) : 0.f;
    float pe_div = 0.f, pa = 0.f;
    if (rowmap == 1 || rowmap == 2) {
        int ci = c & ~1;
        pe_div = expf((float)ci * (-logf(10000.f) / (float)HID));
        int hand = rowmap - 1;
        pa = (c & 1) ? cosf((float)hand * pe_div) : sinf((float)hand * pe_div);
    }
    int rbase = tid >> 6;

    #pragma unroll
    for (int s = 0; s < 2; s++) {
        #pragma unroll
        for (int mi2 = 0; mi2 < 2; mi2++) {
            int mi = s * 2 + mi2;
            #pragma unroll
            for (int ni = 0; ni < 4; ni++)
                #pragma unroll
                for (int reg = 0; reg < 4; reg++) {
                    int r = mi2 * 16 + quad * 4 + reg;   // 0..31
                    int col = ni * 16 + l16;
                    red[wave][r * RSTR + col] = acc[mi][ni][reg];
                }
        }
        __syncthreads();

        #pragma unroll
        for (int j = 0; j < 8; j++) {
            int rr = rbase + (j << 2);   // 0..31
            int idx = rr * RSTR + cc;
            float v = red[0][idx] + red[1][idx] + red[2][idx] + red[3][idx] + bv;
            int r = row0 + s * 32 + rr;
            if (resid) v += resid[(size_t)r * Nn + c];
            if (relu)  v = fmaxf(v, 0.f);
            if (rowmap == 3) {
                int hand = r & 1;
                int l = (r >> 1) & 63, bb = r >> 7;
                if (hand == 0 && c < HANDD) {
                    size_t oi = ((size_t)bb * 64 + l) * HANDD + c;
                    if (isf32) ((float*)Df)[oi] = v;
                    else       ((bf16*)Df)[oi]  = __float2bfloat16(v);
                } else if (hand == 1 && c >= HANDD && c < 2 * HANDD) {
                    size_t oi = (size_t)B_ * L_ * HANDD + ((size_t)bb * 64 + l) * HANDD + (c - HANDD);
                    if (isf32) ((float*)Df)[oi] = v;
                    else       ((bf16*)Df)[oi]  = __float2bfloat16(v);
                }
            } else {
                int orow = r;
                if (rowmap) {
                    int bb = r >> 6, ll = r & 63;
                    orow = bb * S_ + 2 * ll + (rowmap - 1);
                    float pf = (c & 1) ? cosf((float)ll * pe_div) : sinf((float)ll * pe_div);
                    v += pf + pa;
                }
                if (Df) Df[(size_t)orow * Nn + c] = v;
                if (Db) Db[(size_t)orow * Nn + c] = f2bf(v);
            }
        }
        if (s == 0) __syncthreads();   // red reused by stage 1
    }
}

// MFMA attention: one (b,h) per blockIdx.x, row-half per blockIdx.y.
__global__ __launch_bounds__(128) void attn_mfma(
    const unsigned short* __restrict__ qkvb, unsigned short* __restrict__ aob)
{
    __shared__ unsigned short Vt[64 * VSTR];
    __shared__ unsigned short Pb[64 * VSTR];
    int bh = blockIdx.x;
    int b = bh >> 3, h = bh & 7;
    int rowhalf = blockIdx.y;
    int tid = threadIdx.x;
    int w = tid >> 6, lane = tid & 63;
    int quad = lane >> 4, l16 = lane & 15;
    size_t qbase = (size_t)(b * S_) * 1536 + h * DHEAD;

    for (int i = tid; i < S_ * DHEAD; i += 128) {
        int key = i >> 6, dcol = i & 63;
        Vt[dcol * VSTR + key] = qkvb[qbase + (size_t)key * 1536 + 1024 + dcol];
    }
    __syncthreads();

    int qrow0 = rowhalf * 64 + w * 32;
    short8 aQ[2][2];
    #pragma unroll
    for (int mt = 0; mt < 2; mt++)
        #pragma unroll
        for (int kc = 0; kc < 2; kc++)
            aQ[mt][kc] = *(const short8*)&qkvb[qbase + (size_t)(qrow0 + mt*16 + l16) * 1536 + kc*32 + quad*8];

    floatx4 sacc[2][8];
    #pragma unroll
    for (int mt = 0; mt < 2; mt++)
        #pragma unroll
        for (int nt = 0; nt < 8; nt++)
            sacc[mt][nt] = (floatx4){0.f, 0.f, 0.f, 0.f};

    #pragma unroll
    for (int nt = 0; nt < 8; nt++) {
        const unsigned short* kp = &qkvb[qbase + (size_t)(nt*16 + l16) * 1536 + 512 + quad*8];
        short8 bK0 = *(const short8*)kp;
        short8 bK1 = *(const short8*)(kp + 32);
        #pragma unroll
        for (int mt = 0; mt < 2; mt++) {
            sacc[mt][nt] = __builtin_amdgcn_mfma_f32_16x16x32_bf16(aQ[mt][0], bK0, sacc[mt][nt], 0, 0, 0);
            sacc[mt][nt] = __builtin_amdgcn_mfma_f32_16x16x32_bf16(aQ[mt][1], bK1, sacc[mt][nt], 0, 0, 0);
        }
    }

    #pragma unroll
    for (int mt = 0; mt < 2; mt++)
        #pragma unroll
        for (int reg = 0; reg < 4; reg++) {
            float v[8];
            float m = -3.4e38f;
            #pragma unroll
            for (int nt = 0; nt < 8; nt++) { v[nt] = sacc[mt][nt][reg] * 0.125f; m = fmaxf(m, v[nt]); }
            #pragma unroll
            for (int off = 1; off <= 8; off <<= 1) m = fmaxf(m, __shfl_xor(m, off, 64));
            float sum = 0.f;
            #pragma unroll
            for (int nt = 0; nt < 8; nt++) { v[nt] = expf(v[nt] - m); sum += v[nt]; }
            #pragma unroll
            for (int off = 1; off <= 8; off <<= 1) sum += __shfl_xor(sum, off, 64);
            float inv = 1.f / sum;
            int lr = w*32 + mt*16 + quad*4 + reg;
            #pragma unroll
            for (int nt = 0; nt < 8; nt++)
                Pb[lr * VSTR + nt*16 + l16] = f2bf(v[nt] * inv);
        }
    __syncthreads();

    #pragma unroll
    for (int mt = 0; mt < 2; mt++) {
        short8 aP[4];
        #pragma unroll
        for (int kt = 0; kt < 4; kt++)
            aP[kt] = *(const short8*)&Pb[(w*32 + mt*16 + l16) * VSTR + kt*32 + quad*8];
        #pragma unroll
        for (int nt = 0; nt < 4; nt++) {
            floatx4 o = (floatx4){0.f, 0.f, 0.f, 0.f};
            #pragma unroll
            for (int kt = 0; kt < 4; kt++) {
                short8 bV = *(const short8*)&Vt[(nt*16 + l16) * VSTR + kt*32 + quad*8];
                o = __builtin_amdgcn_mfma_f32_16x16x32_bf16(aP[kt], bV, o, 0, 0, 0);
            }
            #pragma unroll
            for (int reg = 0; reg < 4; reg++) {
                int qrow = qrow0 + mt*16 + quad*4 + reg;
                aob[(size_t)(b*S_ + qrow) * HID + h*DHEAD + nt*16 + l16] = f2bf(o[reg]);
            }
        }
    }
}

__global__ __launch_bounds__(256) void ln_kernel(
    const float* __restrict__ src, const void* __restrict__ g,
    const void* __restrict__ bb, size_t goff,
    float* __restrict__ dst, unsigned short* __restrict__ dstb,
    const int* __restrict__ dtf)
{
    int isf32 = dtf[0];
    int t = blockIdx.x;
    const float* x = src + (size_t)t * HID;
    int tid = threadIdx.x, lane = tid & 63, wave = tid >> 6;
    float v0 = x[tid], v1 = x[tid + 256];
    float s = v0 + v1;
    for (int off = 32; off; off >>= 1) s += __shfl_down(s, off, 64);
    __shared__ float wsum[4];
    if (lane == 0) wsum[wave] = s;
    __syncthreads();
    float mu = (wsum[0] + wsum[1] + wsum[2] + wsum[3]) * (1.f / 512.f);
    float d0 = v0 - mu, d1 = v1 - mu;
    float q = d0 * d0 + d1 * d1;
    for (int off = 32; off; off >>= 1) q += __shfl_down(q, off, 64);
    __syncthreads();
    if (lane == 0) wsum[wave] = q;
    __syncthreads();
    float var = (wsum[0] + wsum[1] + wsum[2] + wsum[3]) * (1.f / 512.f);
    float rstd = 1.f / sqrtf(var + 1e-5f);
    float y0 = d0 * rstd * ldin(g, goff + tid, isf32)       + ldin(bb, goff + tid, isf32);
    float y1 = d1 * rstd * ldin(g, goff + tid + 256, isf32) + ldin(bb, goff + tid + 256, isf32);
    if (dst) {
        dst[(size_t)t * HID + tid]       = y0;
        dst[(size_t)t * HID + tid + 256] = y1;
    }
    if (dstb) {
        dstb[(size_t)t * HID + tid]       = f2bf(y0);
        dstb[(size_t)t * HID + tid + 256] = f2bf(y1);
    }
}

extern "C" void kernel_launch(void* const* d_in, const int* in_sizes, int n_in,
                              void* d_out, int out_size, void* d_ws, size_t ws_size,
                              hipStream_t stream)
{
    const void* x_lhand = d_in[0];
    const void* x_rhand = d_in[1];
    const void* j_lhand = d_in[2];
    const void* j_rhand = d_in[3];
    const void* m_contact = d_in[4];
    const void* x_obj = d_in[5];
    const void* point_cloud = d_in[6];
    const void* fc_lw = d_in[7];
    const void* fc_lb = d_in[8];
    const void* fc_rw = d_in[9];
    const void* fc_rb = d_in[10];
    const void* out_lw = d_in[11];
    const void* out_lb = d_in[12];
    const void* out_rw = d_in[13];
    const void* out_rb = d_in[14];
    const void* Wqkv = d_in[15];
    const void* bqkv = d_in[16];
    const void* Wo   = d_in[17];
    const void* bo   = d_in[18];
    const void* W1   = d_in[19];
    const void* b1f  = d_in[20];
    const void* W2   = d_in[21];
    const void* b2fp = d_in[22];
    const void* ln1g = d_in[23];
    const void* ln1b = d_in[24];
    const void* ln2g = d_in[25];
    const void* ln2b = d_in[26];

    float* ws = (float*)d_ws;
    int* dtf = (int*)d_ws;
    float* x     = ws + F_X;
    float* tmp   = ws + F_TMP;
    float* h     = ws + F_H;
    unsigned short* qkvb = (unsigned short*)(ws + F_QKV);
    unsigned short* wb   = (unsigned short*)(ws + WB_F);
    unsigned short* catl = wb + U_CATL;
    unsigned short* catr = wb + U_CATR;
    unsigned short* xb   = wb + U_XB;
    unsigned short* aob  = wb + U_AOB;
    unsigned short* hb   = wb + U_HB;
    unsigned short* ffb  = wb + U_FFB;

    detect_kernel<<<1, 256, 0, stream>>>(m_contact, dtf);

    PrepP pp;
    pp.x_l = x_lhand; pp.x_r = x_rhand; pp.j_l = j_lhand; pp.j_r = j_rhand;
    pp.mc = m_contact; pp.x_obj = x_obj; pp.pc = point_cloud;
    pp.fc_lw = fc_lw; pp.fc_rw = fc_rw; pp.Wqkv = Wqkv; pp.Wo = Wo;
    pp.W1 = W1; pp.W2 = W2; pp.out_lw = out_lw; pp.out_rw = out_rw;
    pp.wb = wb; pp.catl = catl; pp.catr = catr; pp.dtf = dtf;
    prep_all<<<PC_UNITS + NW_UNITS + 1, 256, 0, stream>>>(pp);

    // fc both hands in one dispatch: 2 x (16x8) blocks; PE fused
    gemm_ks<<<256, 256, 0, stream>>>(catl, catr, CATP, wb, W_FCL, W_FCR, 128, HID,
                                     fc_lb, fc_rb, 0, nullptr, x, xb, 0, 1, 8, dtf);

    for (int i = 0; i < NLAY; i++) {
        size_t oWq = (size_t)W_QKV + (size_t)i * 1536 * HID, obq = (size_t)i * 1536;
        size_t oWo = (size_t)W_WO + (size_t)i * HID * HID,   obo = (size_t)i * HID;
        size_t oW1 = (size_t)W_W1 + (size_t)i * 2048 * HID,  ob1 = (size_t)i * 2048;
        size_t oW2 = (size_t)W_W2 + (size_t)i * HID * 2048,  ob2 = (size_t)i * HID;
        size_t oln = (size_t)i * HID;

        // qkv: bf16 output only (consumed by MFMA attention)
        gemm_ks<<<768, 256, 0, stream>>>(xb, nullptr, HID, wb, oWq, 0, 0, 1536,
                                         bqkv, nullptr, obq, nullptr, nullptr, qkvb, 0, 0, 24, dtf);

        attn_mfma<<<dim3(B_ * NHEAD, 2), 128, 0, stream>>>(qkvb, aob);

        gemm_ks<<<256, 256, 0, stream>>>(aob, nullptr, HID, wb, oWo, 0, 0, HID,
                                         bo, nullptr, obo, x, tmp, nullptr, 0, 0, 8, dtf);
        ln_kernel<<<T_, 256, 0, stream>>>(tmp, ln1g, ln1b, oln, h, hb, dtf);

        gemm_ks<<<1024, 256, 0, stream>>>(hb, nullptr, HID, wb, oW1, 0, 0, 2048,
                                          b1f, nullptr, ob1, nullptr, nullptr, ffb, 1, 0, 32, dtf);
        gemm_ks<<<256, 256, 0, stream>>>(ffb, nullptr, 2048, wb, oW2, 0, 0, HID,
                                         b2fp, nullptr, ob2, h, tmp, nullptr, 0, 0, 8, dtf);
        ln_kernel<<<T_, 256, 0, stream>>>(tmp, ln2g, ln2b, oln, x, xb, dtf);
    }

    // out projection: all tokens x Wcomb[256][512], parity epilogue
    gemm_ks<<<128, 256, 0, stream>>>(xb, nullptr, HID, wb, W_OUT, 0, 0, 256,
                                     out_lb, out_rb, 0, nullptr, (float*)d_out, nullptr, 0, 3, 4, dtf);
}

// Round 12
// 635.197 us; speedup vs baseline: 4.5128x; 1.0257x over previous
//
#include <hip/hip_runtime.h>
#include <hip/hip_bf16.h>

typedef __hip_bfloat16 bf16;
typedef __attribute__((ext_vector_type(8))) short short8;
typedef __attribute__((ext_vector_type(4))) float floatx4;

#define B_    16
#define L_    64
#define N_    1024
#define HANDD 99
#define Jn    21
#define HID   512
#define NLAY  4
#define NHEAD 8
#define DHEAD 64
#define CATD  2273
#define CATP  2304
#define S_    128
#define T_    2048

// float workspace offsets
#define F_X     16
#define F_QKV   1048592
#define F_TMP   6291472
#define F_H     7340048
#define WB_F    8388624
// ushort offsets from wb
#define W_FCL   0
#define W_FCR   1179648
#define W_QKV   2359296
#define W_WO    5505024
#define W_W1    6553600
#define W_W2    10747904
#define U_CATL  14942208
#define U_CATR  17301504
#define U_XB    19660800
#define U_AOB   20709376
#define U_HB    21757952
#define W_OUT   22806528
#define U_FFB   U_CATL   // alias: cat buffers dead after fc

#define RSTR 68
#define VSTR 136

// prep_all unit space
#define PC_UNITS 2048      // (b,l) x hand
#define NW_UNITS 3680      // transpose tiles

static __device__ __forceinline__ float b2f(bf16 x) { return __bfloat162float(x); }
static __device__ __forceinline__ float ldin(const void* p, size_t i, int isf32) {
    return isf32 ? ((const float*)p)[i] : b2f(((const bf16*)p)[i]);
}
static __device__ __forceinline__ unsigned short f2bf(float f) {
    unsigned int u = __float_as_uint(f);
    unsigned int r = (u + 0x7fffu + ((u >> 16) & 1u)) >> 16;
    return (unsigned short)r;
}

__global__ __launch_bounds__(256) void detect_kernel(const void* mc, int* flag)
{
    __shared__ int sbad;
    int tid = threadIdx.x;
    if (tid == 0) sbad = 0;
    __syncthreads();
    int bad = 0;
    for (int i = tid; i < 16384; i += 256) {
        float v = b2f(((const bf16*)mc)[i]);
        if (!(v >= -0.02f && v <= 1.02f)) bad = 1;
    }
    if (bad) atomicOr(&sbad, 1);
    __syncthreads();
    if (tid == 0) flag[0] = sbad ? 1 : 0;
}

// ---- merged prep: pctcat (hand-split) + all weight transposes, one dispatch ----
struct PrepP {
    const void *x_l, *x_r, *j_l, *j_r, *mc, *x_obj, *pc;
    const void *fc_lw, *fc_rw, *Wqkv, *Wo, *W1, *W2, *out_lw, *out_rw;
    unsigned short *wb, *catl, *catr;
    const int* dtf;
};

// one (b,l,hand): pc transform + feature row + NN-contact for 21 joints
static __device__ void pctcat_half(int bl, int hand, const PrepP& P, int isf32,
                                   char* smemc)
{
    float* pcl  = (float*)smemc;    // N_*3
    float* pcnl = pcl + N_ * 3;     // N_ (|p|^2)
    int b = bl >> 6;
    int tid = threadIdx.x;

    size_t xo = (size_t)bl * 10;
    float t0 = ldin(P.x_obj, xo+0, isf32), t1 = ldin(P.x_obj, xo+1, isf32), t2 = ldin(P.x_obj, xo+2, isf32);
    float a1x = ldin(P.x_obj, xo+3, isf32), a1y = ldin(P.x_obj, xo+4, isf32), a1z = ldin(P.x_obj, xo+5, isf32);
    float a2x = ldin(P.x_obj, xo+6, isf32), a2y = ldin(P.x_obj, xo+7, isf32), a2z = ldin(P.x_obj, xo+8, isf32);
    float n1 = sqrtf(a1x*a1x + a1y*a1y + a1z*a1z);
    float b1x = a1x / n1, b1y = a1y / n1, b1z = a1z / n1;
    float d = b1x*a2x + b1y*a2y + b1z*a2z;
    float c2x = a2x - d*b1x, c2y = a2y - d*b1y, c2z = a2z - d*b1z;
    float n2 = sqrtf(c2x*c2x + c2y*c2y + c2z*c2z);
    float b2x = c2x / n2, b2y = c2y / n2, b2z = c2z / n2;
    float b3x = b1y*b2z - b1z*b2y;
    float b3y = b1z*b2x - b1x*b2z;
    float b3z = b1x*b2y - b1y*b2x;

    size_t pcb = (size_t)b * N_ * 3;
    for (int n = tid; n < N_; n += 256) {
        float p0 = ldin(P.pc, pcb + n*3+0, isf32);
        float p1 = ldin(P.pc, pcb + n*3+1, isf32);
        float p2 = ldin(P.pc, pcb + n*3+2, isf32);
        float q0 = b1x*p0 + b2x*p1 + b3x*p2 + t0;
        float q1 = b1y*p0 + b2y*p1 + b3y*p2 + t1;
        float q2 = b1z*p0 + b2z*p1 + b3z*p2 + t2;
        pcl[n*3+0] = q0; pcl[n*3+1] = q1; pcl[n*3+2] = q2;
        pcnl[n] = q0*q0 + q1*q1 + q2*q2;
    }
    __syncthreads();

    const void* xh = hand ? P.x_r : P.x_l;
    const void* jh = hand ? P.j_r : P.j_l;
    unsigned short* row = (hand ? P.catr : P.catl) + (size_t)bl * CATP;
    if (!isf32) {
        // bf16 inputs: raw ushort copies (f2bf(b2f(x)) == x) — validated r9/r11
        const unsigned short* xs = (const unsigned short*)xh + (size_t)bl * HANDD;
        const unsigned short* js = (const unsigned short*)jh + (size_t)bl * 63;
        const unsigned short* ms = (const unsigned short*)P.mc + (size_t)b * N_;
        for (int c = tid; c < HANDD; c += 256)  row[c]       = xs[c];
        for (int c = tid; c < 63;    c += 256)  row[99 + c]  = js[c];
        for (int c = tid; c < N_;    c += 256)  row[162 + c] = ms[c];
    } else {
        for (int c = tid; c < HANDD; c += 256)  row[c]       = f2bf(ldin(xh, (size_t)bl*HANDD + c, isf32));
        for (int c = tid; c < 63;    c += 256)  row[99 + c]  = f2bf(ldin(jh, (size_t)bl*63 + c, isf32));
        for (int c = tid; c < N_;    c += 256)  row[162 + c] = f2bf(ldin(P.mc, (size_t)b*N_ + c, isf32));
    }
    for (int c = tid; c < N_;    c += 256)  row[1186 + c] = f2bf(sqrtf(pcnl[c]));
    for (int c = CATD + tid; c < CATP; c += 256) row[c] = 0;

    int wave = tid >> 6, lane = tid & 63;
    for (int j = wave; j < Jn; j += 4) {
        float jx = ldin(jh, (size_t)bl*63 + j*3 + 0, isf32);
        float jy = ldin(jh, (size_t)bl*63 + j*3 + 1, isf32);
        float jz = ldin(jh, (size_t)bl*63 + j*3 + 2, isf32);
        float m2x = -2.f * jx, m2y = -2.f * jy, m2z = -2.f * jz;
        float best = 3.4e38f; int bidx = 0x7fffffff;
        for (int n = lane; n < N_; n += 64) {
            float p0 = pcl[n*3+0], p1 = pcl[n*3+1], p2 = pcl[n*3+2];
            float d2 = fmaf(m2x, p0, fmaf(m2y, p1, fmaf(m2z, p2, pcnl[n])));
            if (d2 < best) { best = d2; bidx = n; }
        }
        for (int off = 32; off; off >>= 1) {
            float ob = __shfl_down(best, off, 64);
            int   oi = __shfl_down(bidx, off, 64);
            if (ob < best || (ob == best && oi < bidx)) { best = ob; bidx = oi; }
        }
        bidx = __shfl(bidx, 0, 64);
        if (lane < 3) {
            float jc = (lane == 0) ? jx : ((lane == 1) ? jy : jz);
            float cc = pcl[bidx*3 + lane];
            float dd = jc - cc;
            row[2210 + j*3 + lane] = f2bf(expf(-50.f * dd * dd));
        }
    }
}

// RACE NOTE (transpose): write guarded by n < NnB. out_lw/out_rw regions abut
// at row 99 (not 64-aligned); unguarded pad writes from the out_lw tiles would
// race with out_rw's real rows 99..127 inside this single dispatch.
__global__ __launch_bounds__(256) void prep_all(PrepP P)
{
    __shared__ __attribute__((aligned(16))) char smem[17536];   // max(bf16 tu 64*137*2, f32 tile 16640, pctcat 16384)
    int isf32 = P.dtf[0];
    int u = blockIdx.x;

    if (u < PC_UNITS) {                 // pctcat: (b,l) x hand
        pctcat_half(u >> 1, u & 1, P, isf32, smem);
        return;
    }
    u -= PC_UNITS;
    if (u == NW_UNITS) {                // zero Wcomb rows 198..255 (read, discarded)
        unsigned short* wz = P.wb + W_OUT + (size_t)(2 * HANDD) * HID;
        for (int idx = threadIdx.x; idx < (256 - 2 * HANDD) * HID; idx += 256)
            wz[idx] = 0;
        return;
    }

    const void* src; unsigned short* dst;
    int K, Nn, NnB, Kpad, gx; size_t soff = 0, doff = 0;
    if (u < 576) {
        int hh = u >= 288; if (hh) u -= 288;
        src = hh ? P.fc_rw : P.fc_lw; dst = P.wb + (hh ? W_FCR : W_FCL);
        K = CATD; Nn = HID; NnB = HID; Kpad = CATP; gx = 8;
    } else if (u < 1344) {
        int r = u - 576; int z = r / 192; u = r % 192;
        src = P.Wqkv; soff = (size_t)z * HID * 1536;
        dst = P.wb + W_QKV; doff = (size_t)z * 1536 * HID;
        K = HID; Nn = 1536; NnB = 1536; Kpad = HID; gx = 24;
    } else if (u < 1600) {
        int r = u - 1344; int z = r / 64; u = r % 64;
        src = P.Wo; soff = (size_t)z * HID * HID;
        dst = P.wb + W_WO; doff = (size_t)z * HID * HID;
        K = HID; Nn = HID; NnB = HID; Kpad = HID; gx = 8;
    } else if (u < 2624) {
        int r = u - 1600; int z = r / 256; u = r % 256;
        src = P.W1; soff = (size_t)z * HID * 2048;
        dst = P.wb + W_W1; doff = (size_t)z * 2048 * HID;
        K = HID; Nn = 2048; NnB = 2048; Kpad = HID; gx = 32;
    } else if (u < 3648) {
        int r = u - 2624; int z = r / 256; u = r % 256;
        src = P.W2; soff = (size_t)z * 2048 * HID;
        dst = P.wb + W_W2; doff = (size_t)z * HID * 2048;
        K = 2048; Nn = HID; NnB = HID; Kpad = 2048; gx = 8;
    } else {
        int r = u - 3648; int hh = r >= 16; if (hh) r -= 16;
        src = hh ? P.out_rw : P.out_lw;
        dst = P.wb + W_OUT + (hh ? (size_t)HANDD * HID : 0);
        K = HID; Nn = HANDD; NnB = HANDD; Kpad = HID; gx = 2; u = r;
    }
    int ntile = u % gx;
    int n0 = ntile * 64, k0 = (u / gx) * 64;
    int tid = threadIdx.x;

    if (!isf32 && (Nn % 8) == 0) {
        // bf16 WIDE path: even n-tile handles 64k x 128n (odd sibling exits).
        // Reads: 16 lanes x 16B = 256B contiguous per k-row (2x r11 contiguity).
        // All bf16-path regions have NnB % 128 == 0 and gx even, so the pair
        // [n0, n0+128) is always fully in range.
        if (ntile & 1) return;
        unsigned short (*tu)[137] = (unsigned short(*)[137])smem;   // [k 0..63][n 0..127]
        const unsigned short* s = (const unsigned short*)src;
        #pragma unroll
        for (int pass = 0; pass < 4; pass++) {
            int r = (tid >> 4) + pass * 16;    // k-row 0..63
            int k = k0 + r;
            int nb = (tid & 15) * 8;           // n-col 0..127
            short8 v = (short8){0,0,0,0,0,0,0,0};
            if (k < K) v = *(const short8*)(s + soff + (size_t)k * Nn + n0 + nb);
            #pragma unroll
            for (int j = 0; j < 8; j++) tu[r][nb + j] = (unsigned short)v[j];
        }
        __syncthreads();
        #pragma unroll
        for (int pass = 0; pass < 4; pass++) {
            int rp = (tid >> 3) + pass * 32;   // n within pair 0..127
            int n = n0 + rp;
            int kb = (tid & 7) * 8;
            short8 o;
            #pragma unroll
            for (int j = 0; j < 8; j++) o[j] = (short)tu[kb + j][rp];
            *(short8*)(dst + doff + (size_t)n * Kpad + k0 + kb) = o;
        }
    } else {
        // f32 (or Nn%8!=0, e.g. out_lw Nn=99) path: scalar via f32 LDS tile
        float (*tile)[65] = (float(*)[65])smem;
        int a = tid & 63, bq = tid >> 6;
        for (int r = bq; r < 64; r += 4) {
            int k = k0 + r, n = n0 + a;
            float v = (k < K && n < NnB) ? ldin(src, soff + (size_t)k * Nn + n, isf32) : 0.f;
            tile[r][a] = v;
        }
        __syncthreads();
        for (int r = bq; r < 64; r += 4) {
            int n = n0 + r;
            if (n < NnB)
                dst[doff + (size_t)n * Kpad + k0 + a] = f2bf(tile[a][r]);
        }
    }
}

// K-split MFMA GEMM: one 64x64 tile per block, 4 waves each take K/4,
// LDS tree-reduce in TWO 32-row stages (34.8KB LDS). rowmap: 0 plain,
// 1/2 fc scatter + fused PE, 3 out-proj parity store. halfgrid: blocks >=
// halfgrid use Ab2/wtoff2/bias2 (rowmap 2).
__global__ __launch_bounds__(256) void gemm_ks(
    const unsigned short* __restrict__ Ab, const unsigned short* __restrict__ Ab2,
    int K,
    const unsigned short* __restrict__ Wt, size_t wtoff, size_t wtoff2, int halfgrid,
    int Nn,
    const void* __restrict__ bias, const void* __restrict__ bias2, size_t boff,
    const float* __restrict__ resid,
    float* __restrict__ Df, unsigned short* __restrict__ Db,
    int relu, int rowmap, int tilesN, const int* __restrict__ dtf)
{
    __shared__ float red[4][32 * RSTR];
    int blk = blockIdx.x;
    if (halfgrid && blk >= halfgrid) {
        blk -= halfgrid; Ab = Ab2; wtoff = wtoff2; bias = bias2; rowmap = 2;
    }
    int tid = threadIdx.x;
    int wave = tid >> 6, lane = tid & 63;
    int quad = lane >> 4, l16 = lane & 15;
    int tm = blk / tilesN, tn = blk - tm * tilesN;
    int row0 = tm << 6, col0 = tn << 6;
    int Ks = K >> 2;
    int ks0 = wave * Ks;

    const unsigned short* Ap = Ab + (size_t)(row0 + l16) * K + ks0 + quad * 8;
    const unsigned short* Bp = Wt + wtoff + (size_t)(col0 + l16) * K + ks0 + quad * 8;
    size_t astep = (size_t)16 * K;

    floatx4 acc[4][4];
    #pragma unroll
    for (int i = 0; i < 4; i++)
        #pragma unroll
        for (int j = 0; j < 4; j++)
            acc[i][j] = (floatx4){0.f, 0.f, 0.f, 0.f};

    for (int k = 0; k < Ks; k += 32) {
        short8 af[4], bf[4];
        #pragma unroll
        for (int i = 0; i < 4; i++) {
            af[i] = *(const short8*)(Ap + i * astep + k);
            bf[i] = *(const short8*)(Bp + i * astep + k);
        }
        #pragma unroll
        for (int mi = 0; mi < 4; mi++)
            #pragma unroll
            for (int ni = 0; ni < 4; ni++)
                acc[mi][ni] = __builtin_amdgcn_mfma_f32_16x16x32_bf16(
                    af[mi], bf[ni], acc[mi][ni], 0, 0, 0);
    }

    // per-column epilogue constants
    int isf32 = dtf[0];
    int cc = tid & 63;
    int c = col0 + cc;
    float bv;
    if (rowmap == 3)
        bv = (c < HANDD) ? ldin(bias, c, isf32)
           : ((c < 2 * HANDD) ? ldin(bias2, c - HANDD, isf32) : 0.f);
    else
        bv = bias ? ldin(bias, boff + c, isf32) : 0.f;
    float pe_div = 0.f, pa = 0.f;
    if (rowmap == 1 || rowmap == 2) {
        int ci = c & ~1;
        pe_div = expf((float)ci * (-logf(10000.f) / (float)HID));
        int hand = rowmap - 1;
        pa = (c & 1) ? cosf((float)hand * pe_div) : sinf((float)hand * pe_div);
    }
    int rbase = tid >> 6;

    #pragma unroll
    for (int s = 0; s < 2; s++) {
        #pragma unroll
        for (int mi2 = 0; mi2 < 2; mi2++) {
            int mi = s * 2 + mi2;
            #pragma unroll
            for (int ni = 0; ni < 4; ni++)
                #pragma unroll
                for (int reg = 0; reg < 4; reg++) {
                    int r = mi2 * 16 + quad * 4 + reg;   // 0..31
                    int col = ni * 16 + l16;
                    red[wave][r * RSTR + col] = acc[mi][ni][reg];
                }
        }
        __syncthreads();

        #pragma unroll
        for (int j = 0; j < 8; j++) {
            int rr = rbase + (j << 2);   // 0..31
            int idx = rr * RSTR + cc;
            float v = red[0][idx] + red[1][idx] + red[2][idx] + red[3][idx] + bv;
            int r = row0 + s * 32 + rr;
            if (resid) v += resid[(size_t)r * Nn + c];
            if (relu)  v = fmaxf(v, 0.f);
            if (rowmap == 3) {
                int hand = r & 1;
                int l = (r >> 1) & 63, bb = r >> 7;
                if (hand == 0 && c < HANDD) {
                    size_t oi = ((size_t)bb * 64 + l) * HANDD + c;
                    if (isf32) ((float*)Df)[oi] = v;
                    else       ((bf16*)Df)[oi]  = __float2bfloat16(v);
                } else if (hand == 1 && c >= HANDD && c < 2 * HANDD) {
                    size_t oi = (size_t)B_ * L_ * HANDD + ((size_t)bb * 64 + l) * HANDD + (c - HANDD);
                    if (isf32) ((float*)Df)[oi] = v;
                    else       ((bf16*)Df)[oi]  = __float2bfloat16(v);
                }
            } else {
                int orow = r;
                if (rowmap) {
                    int bb = r >> 6, ll = r & 63;
                    orow = bb * S_ + 2 * ll + (rowmap - 1);
                    float pf = (c & 1) ? cosf((float)ll * pe_div) : sinf((float)ll * pe_div);
                    v += pf + pa;
                }
                if (Df) Df[(size_t)orow * Nn + c] = v;
                if (Db) Db[(size_t)orow * Nn + c] = f2bf(v);
            }
        }
        if (s == 0) __syncthreads();   // red reused by stage 1
    }
}

// MFMA attention: one (b,h) per blockIdx.x, row-half per blockIdx.y.
__global__ __launch_bounds__(128) void attn_mfma(
    const unsigned short* __restrict__ qkvb, unsigned short* __restrict__ aob)
{
    __shared__ unsigned short Vt[64 * VSTR];
    __shared__ unsigned short Pb[64 * VSTR];
    int bh = blockIdx.x;
    int b = bh >> 3, h = bh & 7;
    int rowhalf = blockIdx.y;
    int tid = threadIdx.x;
    int w = tid >> 6, lane = tid & 63;
    int quad = lane >> 4, l16 = lane & 15;
    size_t qbase = (size_t)(b * S_) * 1536 + h * DHEAD;

    for (int i = tid; i < S_ * DHEAD; i += 128) {
        int key = i >> 6, dcol = i & 63;
        Vt[dcol * VSTR + key] = qkvb[qbase + (size_t)key * 1536 + 1024 + dcol];
    }
    __syncthreads();

    int qrow0 = rowhalf * 64 + w * 32;
    short8 aQ[2][2];
    #pragma unroll
    for (int mt = 0; mt < 2; mt++)
        #pragma unroll
        for (int kc = 0; kc < 2; kc++)
            aQ[mt][kc] = *(const short8*)&qkvb[qbase + (size_t)(qrow0 + mt*16 + l16) * 1536 + kc*32 + quad*8];

    floatx4 sacc[2][8];
    #pragma unroll
    for (int mt = 0; mt < 2; mt++)
        #pragma unroll
        for (int nt = 0; nt < 8; nt++)
            sacc[mt][nt] = (floatx4){0.f, 0.f, 0.f, 0.f};

    #pragma unroll
    for (int nt = 0; nt < 8; nt++) {
        const unsigned short* kp = &qkvb[qbase + (size_t)(nt*16 + l16) * 1536 + 512 + quad*8];
        short8 bK0 = *(const short8*)kp;
        short8 bK1 = *(const short8*)(kp + 32);
        #pragma unroll
        for (int mt = 0; mt < 2; mt++) {
            sacc[mt][nt] = __builtin_amdgcn_mfma_f32_16x16x32_bf16(aQ[mt][0], bK0, sacc[mt][nt], 0, 0, 0);
            sacc[mt][nt] = __builtin_amdgcn_mfma_f32_16x16x32_bf16(aQ[mt][1], bK1, sacc[mt][nt], 0, 0, 0);
        }
    }

    #pragma unroll
    for (int mt = 0; mt < 2; mt++)
        #pragma unroll
        for (int reg = 0; reg < 4; reg++) {
            float v[8];
            float m = -3.4e38f;
            #pragma unroll
            for (int nt = 0; nt < 8; nt++) { v[nt] = sacc[mt][nt][reg] * 0.125f; m = fmaxf(m, v[nt]); }
            #pragma unroll
            for (int off = 1; off <= 8; off <<= 1) m = fmaxf(m, __shfl_xor(m, off, 64));
            float sum = 0.f;
            #pragma unroll
            for (int nt = 0; nt < 8; nt++) { v[nt] = expf(v[nt] - m); sum += v[nt]; }
            #pragma unroll
            for (int off = 1; off <= 8; off <<= 1) sum += __shfl_xor(sum, off, 64);
            float inv = 1.f / sum;
            int lr = w*32 + mt*16 + quad*4 + reg;
            #pragma unroll
            for (int nt = 0; nt < 8; nt++)
                Pb[lr * VSTR + nt*16 + l16] = f2bf(v[nt] * inv);
        }
    __syncthreads();

    #pragma unroll
    for (int mt = 0; mt < 2; mt++) {
        short8 aP[4];
        #pragma unroll
        for (int kt = 0; kt < 4; kt++)
            aP[kt] = *(const short8*)&Pb[(w*32 + mt*16 + l16) * VSTR + kt*32 + quad*8];
        #pragma unroll
        for (int nt = 0; nt < 4; nt++) {
            floatx4 o = (floatx4){0.f, 0.f, 0.f, 0.f};
            #pragma unroll
            for (int kt = 0; kt < 4; kt++) {
                short8 bV = *(const short8*)&Vt[(nt*16 + l16) * VSTR + kt*32 + quad*8];
                o = __builtin_amdgcn_mfma_f32_16x16x32_bf16(aP[kt], bV, o, 0, 0, 0);
            }
            #pragma unroll
            for (int reg = 0; reg < 4; reg++) {
                int qrow = qrow0 + mt*16 + quad*4 + reg;
                aob[(size_t)(b*S_ + qrow) * HID + h*DHEAD + nt*16 + l16] = f2bf(o[reg]);
            }
        }
    }
}

__global__ __launch_bounds__(256) void ln_kernel(
    const float* __restrict__ src, const void* __restrict__ g,
    const void* __restrict__ bb, size_t goff,
    float* __restrict__ dst, unsigned short* __restrict__ dstb,
    const int* __restrict__ dtf)
{
    int isf32 = dtf[0];
    int t = blockIdx.x;
    const float* x = src + (size_t)t * HID;
    int tid = threadIdx.x, lane = tid & 63, wave = tid >> 6;
    float v0 = x[tid], v1 = x[tid + 256];
    float s = v0 + v1;
    for (int off = 32; off; off >>= 1) s += __shfl_down(s, off, 64);
    __shared__ float wsum[4];
    if (lane == 0) wsum[wave] = s;
    __syncthreads();
    float mu = (wsum[0] + wsum[1] + wsum[2] + wsum[3]) * (1.f / 512.f);
    float d0 = v0 - mu, d1 = v1 - mu;
    float q = d0 * d0 + d1 * d1;
    for (int off = 32; off; off >>= 1) q += __shfl_down(q, off, 64);
    __syncthreads();
    if (lane == 0) wsum[wave] = q;
    __syncthreads();
    float var = (wsum[0] + wsum[1] + wsum[2] + wsum[3]) * (1.f / 512.f);
    float rstd = 1.f / sqrtf(var + 1e-5f);
    float y0 = d0 * rstd * ldin(g, goff + tid, isf32)       + ldin(bb, goff + tid, isf32);
    float y1 = d1 * rstd * ldin(g, goff + tid + 256, isf32) + ldin(bb, goff + tid + 256, isf32);
    if (dst) {
        dst[(size_t)t * HID + tid]       = y0;
        dst[(size_t)t * HID + tid + 256] = y1;
    }
    if (dstb) {
        dstb[(size_t)t * HID + tid]       = f2bf(y0);
        dstb[(size_t)t * HID + tid + 256] = f2bf(y1);
    }
}

extern "C" void kernel_launch(void* const* d_in, const int* in_sizes, int n_in,
                              void* d_out, int out_size, void* d_ws, size_t ws_size,
                              hipStream_t stream)
{
    const void* x_lhand = d_in[0];
    const void* x_rhand = d_in[1];
    const void* j_lhand = d_in[2];
    const void* j_rhand = d_in[3];
    const void* m_contact = d_in[4];
    const void* x_obj = d_in[5];
    const void* point_cloud = d_in[6];
    const void* fc_lw = d_in[7];
    const void* fc_lb = d_in[8];
    const void* fc_rw = d_in[9];
    const void* fc_rb = d_in[10];
    const void* out_lw = d_in[11];
    const void* out_lb = d_in[12];
    const void* out_rw = d_in[13];
    const void* out_rb = d_in[14];
    const void* Wqkv = d_in[15];
    const void* bqkv = d_in[16];
    const void* Wo   = d_in[17];
    const void* bo   = d_in[18];
    const void* W1   = d_in[19];
    const void* b1f  = d_in[20];
    const void* W2   = d_in[21];
    const void* b2fp = d_in[22];
    const void* ln1g = d_in[23];
    const void* ln1b = d_in[24];
    const void* ln2g = d_in[25];
    const void* ln2b = d_in[26];

    float* ws = (float*)d_ws;
    int* dtf = (int*)d_ws;
    float* x     = ws + F_X;
    float* tmp   = ws + F_TMP;
    float* h     = ws + F_H;
    unsigned short* qkvb = (unsigned short*)(ws + F_QKV);
    unsigned short* wb   = (unsigned short*)(ws + WB_F);
    unsigned short* catl = wb + U_CATL;
    unsigned short* catr = wb + U_CATR;
    unsigned short* xb   = wb + U_XB;
    unsigned short* aob  = wb + U_AOB;
    unsigned short* hb   = wb + U_HB;
    unsigned short* ffb  = wb + U_FFB;

    detect_kernel<<<1, 256, 0, stream>>>(m_contact, dtf);

    PrepP pp;
    pp.x_l = x_lhand; pp.x_r = x_rhand; pp.j_l = j_lhand; pp.j_r = j_rhand;
    pp.mc = m_contact; pp.x_obj = x_obj; pp.pc = point_cloud;
    pp.fc_lw = fc_lw; pp.fc_rw = fc_rw; pp.Wqkv = Wqkv; pp.Wo = Wo;
    pp.W1 = W1; pp.W2 = W2; pp.out_lw = out_lw; pp.out_rw = out_rw;
    pp.wb = wb; pp.catl = catl; pp.catr = catr; pp.dtf = dtf;
    prep_all<<<PC_UNITS + NW_UNITS + 1, 256, 0, stream>>>(pp);

    // fc both hands in one dispatch: 2 x (16x8) blocks; PE fused
    gemm_ks<<<256, 256, 0, stream>>>(catl, catr, CATP, wb, W_FCL, W_FCR, 128, HID,
                                     fc_lb, fc_rb, 0, nullptr, x, xb, 0, 1, 8, dtf);

    for (int i = 0; i < NLAY; i++) {
        size_t oWq = (size_t)W_QKV + (size_t)i * 1536 * HID, obq = (size_t)i * 1536;
        size_t oWo = (size_t)W_WO + (size_t)i * HID * HID,   obo = (size_t)i * HID;
        size_t oW1 = (size_t)W_W1 + (size_t)i * 2048 * HID,  ob1 = (size_t)i * 2048;
        size_t oW2 = (size_t)W_W2 + (size_t)i * HID * 2048,  ob2 = (size_t)i * HID;
        size_t oln = (size_t)i * HID;

        // qkv: bf16 output only (consumed by MFMA attention)
        gemm_ks<<<768, 256, 0, stream>>>(xb, nullptr, HID, wb, oWq, 0, 0, 1536,
                                         bqkv, nullptr, obq, nullptr, nullptr, qkvb, 0, 0, 24, dtf);

        attn_mfma<<<dim3(B_ * NHEAD, 2), 128, 0, stream>>>(qkvb, aob);

        gemm_ks<<<256, 256, 0, stream>>>(aob, nullptr, HID, wb, oWo, 0, 0, HID,
                                         bo, nullptr, obo, x, tmp, nullptr, 0, 0, 8, dtf);
        ln_kernel<<<T_, 256, 0, stream>>>(tmp, ln1g, ln1b, oln, h, hb, dtf);

        gemm_ks<<<1024, 256, 0, stream>>>(hb, nullptr, HID, wb, oW1, 0, 0, 2048,
                                          b1f, nullptr, ob1, nullptr, nullptr, ffb, 1, 0, 32, dtf);
        gemm_ks<<<256, 256, 0, stream>>>(ffb, nullptr, 2048, wb, oW2, 0, 0, HID,
                                         b2fp, nullptr, ob2, h, tmp, nullptr, 0, 0, 8, dtf);
        ln_kernel<<<T_, 256, 0, stream>>>(tmp, ln2g, ln2b, oln, x, xb, dtf);
    }

    // out projection: all tokens x Wcomb[256][512], parity epilogue
    gemm_ks<<<128, 256, 0, stream>>>(xb, nullptr, HID, wb, W_OUT, 0, 0, 256,
                                     out_lb, out_rb, 0, nullptr, (float*)d_out, nullptr, 0, 3, 4, dtf);
}